// Round 1
// baseline (7248.251 us; speedup 1.0000x reference)
//
#include <hip/hip_runtime.h>
#include <math.h>

// Model dims
// H=512 D=128 L=8 T=64 W=240 CTX=60 NSTEPS=30

__device__ __forceinline__ float sigf(float x) { return 1.f / (1.f + __expf(-x)); }
__device__ __forceinline__ float tanh_f(float x) {
    float e = __expf(2.f * x);           // inf for large x is fine
    return 1.f - 2.f / (e + 1.f);        // -> +1 / -1 saturation, no NaN
}

__device__ __forceinline__ float gld(const float* p) {
    return __hip_atomic_load(p, __ATOMIC_RELAXED, __HIP_MEMORY_SCOPE_AGENT);
}
__device__ __forceinline__ void gst(float* p, float v) {
    __hip_atomic_store(p, v, __ATOMIC_RELAXED, __HIP_MEMORY_SCOPE_AGENT);
}
__device__ __forceinline__ void gbar(int* ctr, int goal) {
    __syncthreads();
    if (threadIdx.x == 0) {
        __hip_atomic_fetch_add(ctr, 1, __ATOMIC_ACQ_REL, __HIP_MEMORY_SCOPE_AGENT);
        while (__hip_atomic_load(ctr, __ATOMIC_ACQUIRE, __HIP_MEMORY_SCOPE_AGENT) < goal) {
            __builtin_amdgcn_s_sleep(2);
        }
    }
    __syncthreads();
}

// ---------------------------------------------------------------------------
// init: zero [hb0 | c_enc | ph1 | ph2 | ctrs] = 249872 floats at ws[0..)
// ---------------------------------------------------------------------------
__global__ void init_k(float* __restrict__ ws) {
    for (int i = blockIdx.x * blockDim.x + threadIdx.x; i < 249872; i += gridDim.x * blockDim.x)
        ws[i] = 0.f;
}

// ---------------------------------------------------------------------------
// Encoder: one launch per time step t.
// grid = 240 blocks: fg = bid>>4 (15 frame groups of 16), ds = bid&15 (32 dims each)
// Each block: gates (128 rows) x 16 frames, K = 512 (Whh) + 128 (Wih), then LSTM update.
// ---------------------------------------------------------------------------
__global__ void __launch_bounds__(256) enc_step(
    int t, const float* __restrict__ data,
    const float* __restrict__ Wih, const float* __restrict__ Whh,
    const float* __restrict__ bih, const float* __restrict__ bhh,
    const float* __restrict__ h_in, float* __restrict__ h_out, float* __restrict__ c)
{
    __shared__ float hs[16][514];
    __shared__ float xs[16][130];
    __shared__ float pool[128 * 34];   // union: Wt[128][34] / gs[128][17]
    float (*Wt)[34] = (float (*)[34])pool;
    float (*gs)[17] = (float (*)[17])pool;

    const int tid = threadIdx.x;
    const int fg = blockIdx.x >> 4, ds = blockIdx.x & 15;
    const int fbase = fg * 16;

    // stage h (16x512) and x_t (16x128)
    for (int i = tid; i < 2048; i += 256) {            // 2048 float4 = 16*512
        int f = i >> 7, c4 = i & 127;
        float4 v = ((const float4*)(h_in + (size_t)(fbase + f) * 512))[c4];
        hs[f][c4 * 4 + 0] = v.x; hs[f][c4 * 4 + 1] = v.y;
        hs[f][c4 * 4 + 2] = v.z; hs[f][c4 * 4 + 3] = v.w;
    }
    for (int i = tid; i < 512; i += 256) {             // 512 float4 = 16*128
        int f = i >> 5, c4 = i & 31;
        float4 v = ((const float4*)(data + ((size_t)t * 240 + fbase + f) * 128))[c4];
        xs[f][c4 * 4 + 0] = v.x; xs[f][c4 * 4 + 1] = v.y;
        xs[f][c4 * 4 + 2] = v.z; xs[f][c4 * 4 + 3] = v.w;
    }

    const int rp = tid >> 2;            // 0..63 -> rows {2rp, 2rp+1}
    const int fq = tid & 3;             // frames {4fq..4fq+3}
    const int lr0 = 2 * rp, lr1 = lr0 + 1;
    const int grow0 = (lr0 >> 5) * 512 + ds * 32 + (lr0 & 31);
    const int grow1 = (lr1 >> 5) * 512 + ds * 32 + (lr1 & 31);

    float acc0[4], acc1[4];
    {
        float b0 = bih[grow0] + bhh[grow0];
        float b1 = bih[grow1] + bhh[grow1];
#pragma unroll
        for (int j = 0; j < 4; ++j) { acc0[j] = b0; acc1[j] = b1; }
    }
    __syncthreads();

    // Whh part: K=512, tiles of 32
    for (int kt = 0; kt < 512; kt += 32) {
        for (int i = tid; i < 1024; i += 256) {        // 128 rows x 8 float4
            int lr = i >> 3, c4 = i & 7;
            int gr = (lr >> 5) * 512 + ds * 32 + (lr & 31);
            float4 v = ((const float4*)(Whh + (size_t)gr * 512 + kt))[c4];
            Wt[lr][c4 * 4 + 0] = v.x; Wt[lr][c4 * 4 + 1] = v.y;
            Wt[lr][c4 * 4 + 2] = v.z; Wt[lr][c4 * 4 + 3] = v.w;
        }
        __syncthreads();
        const float2* w0p = (const float2*)(&Wt[lr0][0]);
        const float2* w1p = (const float2*)(&Wt[lr1][0]);
#pragma unroll 8
        for (int kh = 0; kh < 16; ++kh) {
            float2 w0 = w0p[kh], w1 = w1p[kh];
#pragma unroll
            for (int j = 0; j < 4; ++j) {
                float2 hv = ((const float2*)(&hs[4 * fq + j][kt]))[kh];
                acc0[j] += w0.x * hv.x + w0.y * hv.y;
                acc1[j] += w1.x * hv.x + w1.y * hv.y;
            }
        }
        __syncthreads();
    }
    // Wih part: K=128, tiles of 32
    for (int kt = 0; kt < 128; kt += 32) {
        for (int i = tid; i < 1024; i += 256) {
            int lr = i >> 3, c4 = i & 7;
            int gr = (lr >> 5) * 512 + ds * 32 + (lr & 31);
            float4 v = ((const float4*)(Wih + (size_t)gr * 128 + kt))[c4];
            Wt[lr][c4 * 4 + 0] = v.x; Wt[lr][c4 * 4 + 1] = v.y;
            Wt[lr][c4 * 4 + 2] = v.z; Wt[lr][c4 * 4 + 3] = v.w;
        }
        __syncthreads();
        const float2* w0p = (const float2*)(&Wt[lr0][0]);
        const float2* w1p = (const float2*)(&Wt[lr1][0]);
#pragma unroll 8
        for (int kh = 0; kh < 16; ++kh) {
            float2 w0 = w0p[kh], w1 = w1p[kh];
#pragma unroll
            for (int j = 0; j < 4; ++j) {
                float2 xv = ((const float2*)(&xs[4 * fq + j][kt]))[kh];
                acc0[j] += w0.x * xv.x + w0.y * xv.y;
                acc1[j] += w1.x * xv.x + w1.y * xv.y;
            }
        }
        __syncthreads();
    }

    // gates -> LDS (reuses Wt pool; sync above separates)
#pragma unroll
    for (int j = 0; j < 4; ++j) {
        gs[lr0][4 * fq + j] = acc0[j];
        gs[lr1][4 * fq + j] = acc1[j];
    }
    __syncthreads();

    // LSTM pointwise update: 512 (frame,dim) pairs
    for (int p = tid; p < 512; p += 256) {
        int f = p >> 5, dl = p & 31;
        float gi = gs[dl][f], gf = gs[32 + dl][f], gg = gs[64 + dl][f], go = gs[96 + dl][f];
        int b = fbase + f, dg = ds * 32 + dl;
        size_t idx = (size_t)b * 512 + dg;
        float cc = c[idx];
        float cn = sigf(gf) * cc + sigf(gi) * tanh_f(gg);
        float hn = sigf(go) * tanh_f(cn);
        c[idx] = cn;
        h_out[idx] = hn;
    }
}

// ---------------------------------------------------------------------------
// Generic xp GEMM: C[M][2048] = A[M][K] @ Wv[2048][K]^T + ba + bb
// rev: A row index reversed (backward LSTM input). grid = Mtiles*16 blocks.
// ---------------------------------------------------------------------------
__global__ void __launch_bounds__(256) gemm_xp(
    const float* __restrict__ A, int M, int K, int rev,
    const float* __restrict__ Wv, const float* __restrict__ ba, const float* __restrict__ bb,
    float* __restrict__ C)
{
    __shared__ float At[16][66];
    __shared__ float Wt[128][66];
    const int tid = threadIdx.x;
    const int nt = blockIdx.x & 15, mt = blockIdx.x >> 4;
    const int rp = tid >> 2, fq = tid & 3;
    const int lr0 = 2 * rp, lr1 = lr0 + 1;
    const int n0 = nt * 128 + lr0, n1 = n0 + 1;

    float acc0[4], acc1[4];
    {
        float b0 = ba[n0] + bb[n0], b1 = ba[n1] + bb[n1];
#pragma unroll
        for (int j = 0; j < 4; ++j) { acc0[j] = b0; acc1[j] = b1; }
    }

    for (int kt = 0; kt < K; kt += 64) {
        {   // A tile: 16 rows x 16 float4 = exactly 256 threads
            int f = tid >> 4, c4 = tid & 15;
            int m = mt * 16 + f;
            float4 v = make_float4(0.f, 0.f, 0.f, 0.f);
            if (m < M) {
                int ar = rev ? (M - 1 - m) : m;
                v = ((const float4*)(A + (size_t)ar * K + kt))[c4];
            }
            At[f][c4 * 4 + 0] = v.x; At[f][c4 * 4 + 1] = v.y;
            At[f][c4 * 4 + 2] = v.z; At[f][c4 * 4 + 3] = v.w;
        }
        for (int i = tid; i < 2048; i += 256) {        // W tile 128x16 float4
            int lr = i >> 4, c4 = i & 15;
            float4 v = ((const float4*)(Wv + (size_t)(nt * 128 + lr) * K + kt))[c4];
            Wt[lr][c4 * 4 + 0] = v.x; Wt[lr][c4 * 4 + 1] = v.y;
            Wt[lr][c4 * 4 + 2] = v.z; Wt[lr][c4 * 4 + 3] = v.w;
        }
        __syncthreads();
        const float2* w0p = (const float2*)(&Wt[lr0][0]);
        const float2* w1p = (const float2*)(&Wt[lr1][0]);
#pragma unroll 8
        for (int kh = 0; kh < 32; ++kh) {
            float2 w0 = w0p[kh], w1 = w1p[kh];
#pragma unroll
            for (int j = 0; j < 4; ++j) {
                float2 av = ((const float2*)(&At[4 * fq + j][0]))[kh];
                acc0[j] += w0.x * av.x + w0.y * av.y;
                acc1[j] += w1.x * av.x + w1.y * av.y;
            }
        }
        __syncthreads();
    }
#pragma unroll
    for (int j = 0; j < 4; ++j) {
        int m = mt * 16 + 4 * fq + j;
        if (m < M) {
            C[(size_t)m * 2048 + n0] = acc0[j];
            C[(size_t)m * 2048 + n1] = acc1[j];
        }
    }
}

// ---------------------------------------------------------------------------
// Pyramidal bi-LSTM recurrence (batch=1), persistent kernel.
// grid = 256 blocks: dir = bid>>7, blk = bid&127 -> 4 h-dims (16 gate rows) per block.
// Whh slice LDS-resident. Spin barrier per step (goal = (t+1)*256).
// outF[t] = forward h ; outB[steps-1-t] = backward h (original-position indexed).
// ---------------------------------------------------------------------------
__global__ void __launch_bounds__(256) pyr_rec(
    const float* __restrict__ xpF, const float* __restrict__ xpB,
    const float* __restrict__ WhhF, const float* __restrict__ WhhB,
    float* __restrict__ hbuf,  // [2][2][512] : [buf][dir][h]
    float* __restrict__ outF, float* __restrict__ outB,
    int steps, int* __restrict__ ctr)
{
    const int tid = threadIdx.x;
    const int dir = blockIdx.x >> 7, blk = blockIdx.x & 127;
    const float* xp  = dir ? xpB : xpF;
    const float* Whh = dir ? WhhB : WhhF;
    float* outp = dir ? outB : outF;

    __shared__ float Wl[16][513];
    __shared__ float hcur[512];
    __shared__ float red[16][17];
    __shared__ float gv[16];

    for (int i = tid; i < 2048; i += 256) {            // 16 rows x 128 float4
        int lr = i >> 7, c4 = i & 127;
        int gr = (lr >> 2) * 512 + blk * 4 + (lr & 3);
        float4 v = ((const float4*)(Whh + (size_t)gr * 512))[c4];
        Wl[lr][c4 * 4 + 0] = v.x; Wl[lr][c4 * 4 + 1] = v.y;
        Wl[lr][c4 * 4 + 2] = v.z; Wl[lr][c4 * 4 + 3] = v.w;
    }
    float creg = 0.f;
    const int lr = tid & 15, seg = tid >> 4;           // 16 segs x 32 k
    __syncthreads();

    for (int t = 0; t < steps; ++t) {
        int hb = t & 1;
        for (int i = tid; i < 512; i += 256)
            hcur[i] = gld(&hbuf[(hb * 2 + dir) * 512 + i]);
        __syncthreads();

        float a = 0.f;
        const float* wr = &Wl[lr][seg * 32];
        const float* hr = &hcur[seg * 32];
#pragma unroll 8
        for (int k = 0; k < 32; ++k) a += wr[k] * hr[k];
        red[lr][seg] = a;
        __syncthreads();

        if (tid < 16) {
            int gr = (tid >> 2) * 512 + blk * 4 + (tid & 3);
            float g = xp[(size_t)t * 2048 + gr];
#pragma unroll
            for (int s = 0; s < 16; ++s) g += red[tid][s];
            gv[tid] = g;
        }
        __syncthreads();
        if (tid < 4) {
            float i_ = sigf(gv[tid]);
            float f_ = sigf(gv[4 + tid]);
            float g_ = tanh_f(gv[8 + tid]);
            float o_ = sigf(gv[12 + tid]);
            creg = f_ * creg + i_ * g_;
            float hn = o_ * tanh_f(creg);
            int d = blk * 4 + tid;
            gst(&hbuf[((1 - hb) * 2 + dir) * 512 + d], hn);
            int row = dir ? (steps - 1 - t) : t;
            outp[(size_t)row * 512 + d] = hn;
        }
        gbar(ctr, (t + 1) * 256);
    }
}

// ---------------------------------------------------------------------------
// x2[j][k] = [f1[2j], b1o[2j], f1[2j+1], b1o[2j+1]]
// ---------------------------------------------------------------------------
__global__ void x2_assemble(const float* __restrict__ f1, const float* __restrict__ b1o,
                            float* __restrict__ x2)
{
    int j = blockIdx.x;
    for (int k = threadIdx.x; k < 2048; k += 256) {
        int q = k >> 9, r = k & 511;
        const float* src = (q & 1) ? b1o : f1;
        int row = 2 * j + (q >> 1);
        x2[(size_t)j * 2048 + k] = src[(size_t)row * 512 + r];
    }
}

// ctx[j] = [f2[j], b2o[j]] ; hdec = f2[59] ; inp = one_hot(7)
__global__ void ctx_k(const float* __restrict__ f2, const float* __restrict__ b2o,
                      float* __restrict__ ctx, float* __restrict__ hdec, float* __restrict__ inp)
{
    int j = blockIdx.x;
    for (int k = threadIdx.x; k < 1024; k += 256)
        ctx[(size_t)j * 1024 + k] = (k < 512) ? f2[(size_t)j * 512 + k]
                                              : b2o[(size_t)j * 512 + k - 512];
    if (j == 0) {
        for (int i = threadIdx.x; i < 512; i += 256) hdec[i] = f2[59 * 512 + i];
        if (threadIdx.x < 8) inp[threadIdx.x] = (threadIdx.x == 7) ? 1.f : 0.f;
    }
}

// ---------------------------------------------------------------------------
// Decoder: 30 autoregressive steps, persistent, 32 blocks, 4 barriers/step.
// ---------------------------------------------------------------------------
__global__ void __launch_bounds__(256) dec_k(
    const float* __restrict__ attn_W, const float* __restrict__ attn_b,
    const float* __restrict__ comb_W, const float* __restrict__ comb_b,
    const float* __restrict__ gWih, const float* __restrict__ gWhh,
    const float* __restrict__ gbih, const float* __restrict__ gbhh,
    const float* __restrict__ outW, const float* __restrict__ outb,
    const float* __restrict__ ctx,
    float* __restrict__ hdec, float* __restrict__ inp,
    float* __restrict__ applied, float* __restrict__ obuf,
    float* __restrict__ dout, int* __restrict__ ctr)
{
    const int tid = threadIdx.x, bid = blockIdx.x;
    const int dbase = bid * 16;
    __shared__ float hl[512], apl[1024], ol[512], hnl[512];
    __shared__ float inpl[8];
    __shared__ float ghl[48], gil[48];
    __shared__ float redg[48][5];
    __shared__ float redA[60][5];
    __shared__ float zl[64], awl[60];
    __shared__ float redB[16][17];
    __shared__ float redD[8][33];
    __shared__ float mss[2];

    for (int s = 0; s < 30; ++s) {
        // ---- stage A: gh (all blocks) + attention/applied (block 0) ----
        if (tid < 8) inpl[tid] = gld(&inp[tid]);
        for (int i = tid; i < 512; i += 256) hl[i] = gld(&hdec[i]);
        __syncthreads();
        {
            int rn = tid >> 2, sg = tid & 3;
            if (rn < 48) {
                int q = rn >> 4, j = rn & 15;
                int r = q * 512 + dbase + j;
                const float* wr = gWhh + (size_t)r * 512 + sg * 128;
                const float* hp = hl + sg * 128;
                float a = 0.f;
#pragma unroll 8
                for (int k = 0; k < 128; ++k) a += wr[k] * hp[k];
                redg[rn][sg] = a;
            }
        }
        __syncthreads();
        if (tid < 48) {
            int q = tid >> 4, j = tid & 15;
            int r = q * 512 + dbase + j;
            ghl[tid] = gbhh[r] + redg[tid][0] + redg[tid][1] + redg[tid][2] + redg[tid][3];
        }
        if (bid == 0) {
            {
                int rn = tid >> 2, sg = tid & 3;
                if (rn < 60) {
                    int k0 = sg * 130;
                    const float* wr = attn_W + (size_t)rn * 520 + k0;
                    float a = 0.f;
                    for (int k = 0; k < 130; ++k) {
                        int kk = k0 + k;
                        float x = (kk < 8) ? inpl[kk] : hl[kk - 8];
                        a += wr[k] * x;
                    }
                    redA[rn][sg] = a;
                }
            }
            __syncthreads();
            if (tid < 60)
                zl[tid] = attn_b[tid] + redA[tid][0] + redA[tid][1] + redA[tid][2] + redA[tid][3];
            __syncthreads();
            if (tid == 0) {
                float m = zl[0];
                for (int j = 1; j < 60; ++j) m = fmaxf(m, zl[j]);
                float ss = 0.f;
                for (int j = 0; j < 60; ++j) { float e = __expf(zl[j] - m); awl[j] = e; ss += e; }
                mss[0] = 1.f / ss;
            }
            __syncthreads();
            float inv = mss[0];
            for (int k = tid; k < 1024; k += 256) {
                float a = 0.f;
                for (int j = 0; j < 60; ++j) a += awl[j] * ctx[(size_t)j * 1024 + k];
                gst(&applied[k], a * inv);
            }
        }
        gbar(ctr, (s * 4 + 1) * 32);

        // ---- stage B: o = relu(comb_W @ [inp; applied] + comb_b) ----
        for (int i = tid; i < 1024; i += 256) apl[i] = gld(&applied[i]);
        __syncthreads();
        {
            int row = tid >> 4, sg = tid & 15;
            int orow = dbase + row;
            int k0 = sg * 65;
            const float* wr = comb_W + (size_t)orow * 1032;
            float a = 0.f;
            for (int k = k0; k < k0 + 65 && k < 1032; ++k) {
                float x = (k < 8) ? inpl[k] : apl[k - 8];
                a += wr[k] * x;
            }
            redB[row][sg] = a;
        }
        __syncthreads();
        if (tid < 16) {
            float a = comb_b[dbase + tid];
#pragma unroll
            for (int sg = 0; sg < 16; ++sg) a += redB[tid][sg];
            gst(&obuf[dbase + tid], fmaxf(a, 0.f));
        }
        gbar(ctr, (s * 4 + 2) * 32);

        // ---- stage C: gi, GRU combine, h_new ----
        for (int i = tid; i < 512; i += 256) ol[i] = gld(&obuf[i]);
        __syncthreads();
        {
            int rn = tid >> 2, sg = tid & 3;
            if (rn < 48) {
                int q = rn >> 4, j = rn & 15;
                int r = q * 512 + dbase + j;
                const float* wr = gWih + (size_t)r * 512 + sg * 128;
                const float* op = ol + sg * 128;
                float a = 0.f;
#pragma unroll 8
                for (int k = 0; k < 128; ++k) a += wr[k] * op[k];
                redg[rn][sg] = a;
            }
        }
        __syncthreads();
        if (tid < 48) {
            int q = tid >> 4, j = tid & 15;
            int r = q * 512 + dbase + j;
            gil[tid] = gbih[r] + redg[tid][0] + redg[tid][1] + redg[tid][2] + redg[tid][3];
        }
        __syncthreads();
        if (tid < 16) {
            float r_ = sigf(gil[tid] + ghl[tid]);
            float z_ = sigf(gil[16 + tid] + ghl[16 + tid]);
            float n_ = tanh_f(gil[32 + tid] + r_ * ghl[32 + tid]);
            float hnew = (1.f - z_) * n_ + z_ * hl[dbase + tid];
            gst(&hdec[dbase + tid], hnew);
        }
        gbar(ctr, (s * 4 + 3) * 32);

        // ---- stage D: logits + log_softmax (block 0) ----
        if (bid == 0) {
            for (int i = tid; i < 512; i += 256) hnl[i] = gld(&hdec[i]);
            __syncthreads();
            {
                int l = tid >> 5, sg = tid & 31;
                const float* wr = outW + (size_t)l * 512 + sg * 16;
                const float* hp = hnl + sg * 16;
                float a = 0.f;
#pragma unroll
                for (int k = 0; k < 16; ++k) a += wr[k] * hp[k];
                redD[l][sg] = a;
            }
            __syncthreads();
            if (tid < 8) {
                float a = outb[tid];
#pragma unroll
                for (int sg = 0; sg < 32; ++sg) a += redD[tid][sg];
                zl[tid] = a;
            }
            __syncthreads();
            if (tid == 0) {
                float m = zl[0];
                for (int l = 1; l < 8; ++l) m = fmaxf(m, zl[l]);
                float ss = 0.f;
                for (int l = 0; l < 8; ++l) ss += __expf(zl[l] - m);
                mss[1] = m + __logf(ss);
            }
            __syncthreads();
            if (tid < 8) {
                float lp = zl[tid] - mss[1];
                dout[s * 8 + tid] = lp;     // plain store: only host reads after kernel
                gst(&inp[tid], lp);
            }
        }
        gbar(ctr, (s * 4 + 4) * 32);
    }
}

// ---------------------------------------------------------------------------
extern "C" void kernel_launch(void* const* d_in, const int* in_sizes, int n_in,
                              void* d_out, int out_size, void* d_ws, size_t ws_size,
                              hipStream_t stream) {
    (void)in_sizes; (void)n_in; (void)out_size; (void)ws_size;
    const float* data    = (const float*)d_in[0];
    const float* enc_Wih = (const float*)d_in[1];
    const float* enc_Whh = (const float*)d_in[2];
    const float* enc_bih = (const float*)d_in[3];
    const float* enc_bhh = (const float*)d_in[4];
    const float* p1f_Wih = (const float*)d_in[5];
    const float* p1f_Whh = (const float*)d_in[6];
    const float* p1f_bih = (const float*)d_in[7];
    const float* p1f_bhh = (const float*)d_in[8];
    const float* p1b_Wih = (const float*)d_in[9];
    const float* p1b_Whh = (const float*)d_in[10];
    const float* p1b_bih = (const float*)d_in[11];
    const float* p1b_bhh = (const float*)d_in[12];
    const float* p2f_Wih = (const float*)d_in[13];
    const float* p2f_Whh = (const float*)d_in[14];
    const float* p2f_bih = (const float*)d_in[15];
    const float* p2f_bhh = (const float*)d_in[16];
    const float* p2b_Wih = (const float*)d_in[17];
    const float* p2b_Whh = (const float*)d_in[18];
    const float* p2b_bih = (const float*)d_in[19];
    const float* p2b_bhh = (const float*)d_in[20];
    const float* attn_W  = (const float*)d_in[21];
    const float* attn_b  = (const float*)d_in[22];
    const float* comb_W  = (const float*)d_in[23];
    const float* comb_b  = (const float*)d_in[24];
    const float* gru_Wih = (const float*)d_in[25];
    const float* gru_Whh = (const float*)d_in[26];
    const float* gru_bih = (const float*)d_in[27];
    const float* gru_bhh = (const float*)d_in[28];
    const float* out_W   = (const float*)d_in[29];
    const float* out_b   = (const float*)d_in[30];

    float* ws = (float*)d_ws;
    float* hb0   = ws;                 // 122880
    float* cenc  = ws + 122880;        // 122880
    float* ph1   = ws + 245760;        // 2048
    float* ph2   = ws + 247808;        // 2048
    int*   ctrs  = (int*)(ws + 249856);// 16 ints
    float* hb1   = ws + 249872;        // 122880
    float* xp1f  = ws + 372752;        // 245760
    float* xp1b  = ws + 618512;        // 245760
    float* f1    = ws + 864272;        // 61440
    float* b1o   = ws + 925712;        // 61440
    float* x2    = ws + 987152;        // 122880
    float* xp2f  = ws + 1110032;       // 122880
    float* xp2b  = ws + 1232912;       // 122880
    float* f2    = ws + 1355792;       // 30720
    float* b2o   = ws + 1386512;       // 30720
    float* ctxb  = ws + 1417232;       // 61440
    float* hdec  = ws + 1478672;       // 512
    float* inp   = ws + 1479184;       // 16
    float* appl  = ws + 1479200;       // 1024
    float* obuf  = ws + 1480224;       // 512

    init_k<<<256, 256, 0, stream>>>(ws);

    float* hbs[2] = {hb0, hb1};
    for (int t = 0; t < 64; ++t)
        enc_step<<<240, 256, 0, stream>>>(t, data, enc_Wih, enc_Whh, enc_bih, enc_bhh,
                                          hbs[t & 1], hbs[(t + 1) & 1], cenc);
    // h_enc = hb0 (after 64 steps); x1 = h_enc.reshape(120,1024) (zero-copy)
    gemm_xp<<<128, 256, 0, stream>>>(hb0, 120, 1024, 0, p1f_Wih, p1f_bih, p1f_bhh, xp1f);
    gemm_xp<<<128, 256, 0, stream>>>(hb0, 120, 1024, 1, p1b_Wih, p1b_bih, p1b_bhh, xp1b);
    pyr_rec<<<256, 256, 0, stream>>>(xp1f, xp1b, p1f_Whh, p1b_Whh, ph1, f1, b1o, 120, ctrs + 0);
    x2_assemble<<<60, 256, 0, stream>>>(f1, b1o, x2);
    gemm_xp<<<64, 256, 0, stream>>>(x2, 60, 2048, 0, p2f_Wih, p2f_bih, p2f_bhh, xp2f);
    gemm_xp<<<64, 256, 0, stream>>>(x2, 60, 2048, 1, p2b_Wih, p2b_bih, p2b_bhh, xp2b);
    pyr_rec<<<256, 256, 0, stream>>>(xp2f, xp2b, p2f_Whh, p2b_Whh, ph2, f2, b2o, 60, ctrs + 1);
    ctx_k<<<60, 256, 0, stream>>>(f2, b2o, ctxb, hdec, inp);
    dec_k<<<32, 256, 0, stream>>>(attn_W, attn_b, comb_W, comb_b,
                                  gru_Wih, gru_Whh, gru_bih, gru_bhh,
                                  out_W, out_b, ctxb, hdec, inp, appl, obuf,
                                  (float*)d_out, ctrs + 2);
}

// Round 2
// 4558.496 us; speedup vs baseline: 1.5901x; 1.5901x over previous
//
#include <hip/hip_runtime.h>
#include <math.h>

// Model dims: H=512 D=128 L=8 T=64 W=240 CTX=60 NSTEPS=30

__device__ __forceinline__ float sigf(float x) { return 1.f / (1.f + __expf(-x)); }
__device__ __forceinline__ float tanh_f(float x) {
    float e = __expf(2.f * x);
    return 1.f - 2.f / (e + 1.f);
}

__device__ __forceinline__ float gld(const float* p) {
    return __hip_atomic_load(p, __ATOMIC_RELAXED, __HIP_MEMORY_SCOPE_AGENT);
}
__device__ __forceinline__ void gst(float* p, float v) {
    __hip_atomic_store(p, v, __ATOMIC_RELAXED, __HIP_MEMORY_SCOPE_AGENT);
}

// arrive counter at bar[0], release epoch at bar[16] (separate cache lines).
// Pollers spin on the (write-once-per-epoch) release word, not the counter.
__device__ __forceinline__ void gbarrier(int* bar, int nblk, int ep) {
    __syncthreads();
    if (threadIdx.x == 0) {
        int prev = __hip_atomic_fetch_add(&bar[0], 1, __ATOMIC_ACQ_REL, __HIP_MEMORY_SCOPE_AGENT);
        if (prev == nblk - 1) {
            __hip_atomic_store(&bar[0], 0, __ATOMIC_RELAXED, __HIP_MEMORY_SCOPE_AGENT);
            __hip_atomic_store(&bar[16], ep, __ATOMIC_RELEASE, __HIP_MEMORY_SCOPE_AGENT);
        } else {
            while (__hip_atomic_load(&bar[16], __ATOMIC_ACQUIRE, __HIP_MEMORY_SCOPE_AGENT) < ep)
                __builtin_amdgcn_s_sleep(1);
        }
    }
    __syncthreads();
}

// ---------------------------------------------------------------------------
// init: zero [hb0 | c_enc | ph1 | ph2 | bars] = 250112 floats
// ---------------------------------------------------------------------------
__global__ void init_k(float* __restrict__ ws) {
    for (int i = blockIdx.x * blockDim.x + threadIdx.x; i < 250112; i += gridDim.x * blockDim.x)
        ws[i] = 0.f;
}

// ---------------------------------------------------------------------------
// Encoder, one launch per step. grid 240 = fg(15)*ds(16).
// Block: 128 gate rows (32 dims) x 16 frames, K=640 (h 512 + x 128).
// Activations LDS-resident (staged once, ONE barrier); weights streamed from
// L2 per-thread (rows owned by thread). 8 acc/thread (2 rows x 4 frames).
// ---------------------------------------------------------------------------
__global__ void __launch_bounds__(256) enc_step(
    int t, const float* __restrict__ data,
    const float* __restrict__ Wih, const float* __restrict__ Whh,
    const float* __restrict__ bih, const float* __restrict__ bhh,
    const float* __restrict__ h_in, float* __restrict__ h_out, float* __restrict__ c)
{
    __shared__ float act[16][652];   // [frame][k]; k<512 = h, k>=512 = x
    __shared__ float gs[128][17];    // gate results [row][frame]

    const int tid = threadIdx.x;
    const int fg = blockIdx.x >> 4, ds = blockIdx.x & 15;
    const int fbase = fg * 16;

    for (int i = tid; i < 2048; i += 256) {            // h: 16x128 float4
        int f = i >> 7, c4 = i & 127;
        float4 v = ((const float4*)(h_in + (size_t)(fbase + f) * 512))[c4];
        *(float4*)&act[f][c4 * 4] = v;
    }
    for (int i = tid; i < 512; i += 256) {             // x: 16x32 float4
        int f = i >> 5, c4 = i & 31;
        float4 v = ((const float4*)(data + ((size_t)t * 240 + fbase + f) * 128))[c4];
        *(float4*)&act[f][512 + c4 * 4] = v;
    }

    const int rp = tid >> 2, fq = tid & 3;
    const int lr0 = 2 * rp, lr1 = lr0 + 1;
    const int grow0 = (lr0 >> 5) * 512 + ds * 32 + (lr0 & 31);
    const int grow1 = (lr1 >> 5) * 512 + ds * 32 + (lr1 & 31);

    float acc0[4], acc1[4];
    {
        float b0 = bih[grow0] + bhh[grow0];
        float b1 = bih[grow1] + bhh[grow1];
#pragma unroll
        for (int j = 0; j < 4; ++j) { acc0[j] = b0; acc1[j] = b1; }
    }
    __syncthreads();

    const float* a0 = &act[4 * fq + 0][0];
    const float* a1 = &act[4 * fq + 1][0];
    const float* a2 = &act[4 * fq + 2][0];
    const float* a3 = &act[4 * fq + 3][0];

    {
        const float* w0p = Whh + (size_t)grow0 * 512;
        const float* w1p = Whh + (size_t)grow1 * 512;
#pragma unroll 4
        for (int k = 0; k < 512; k += 4) {
            float4 w0 = *(const float4*)(w0p + k);
            float4 w1 = *(const float4*)(w1p + k);
            float4 v0 = *(const float4*)(a0 + k);
            float4 v1 = *(const float4*)(a1 + k);
            float4 v2 = *(const float4*)(a2 + k);
            float4 v3 = *(const float4*)(a3 + k);
            acc0[0] += w0.x*v0.x + w0.y*v0.y + w0.z*v0.z + w0.w*v0.w;
            acc0[1] += w0.x*v1.x + w0.y*v1.y + w0.z*v1.z + w0.w*v1.w;
            acc0[2] += w0.x*v2.x + w0.y*v2.y + w0.z*v2.z + w0.w*v2.w;
            acc0[3] += w0.x*v3.x + w0.y*v3.y + w0.z*v3.z + w0.w*v3.w;
            acc1[0] += w1.x*v0.x + w1.y*v0.y + w1.z*v0.z + w1.w*v0.w;
            acc1[1] += w1.x*v1.x + w1.y*v1.y + w1.z*v1.z + w1.w*v1.w;
            acc1[2] += w1.x*v2.x + w1.y*v2.y + w1.z*v2.z + w1.w*v2.w;
            acc1[3] += w1.x*v3.x + w1.y*v3.y + w1.z*v3.z + w1.w*v3.w;
        }
    }
    {
        const float* u0p = Wih + (size_t)grow0 * 128;
        const float* u1p = Wih + (size_t)grow1 * 128;
#pragma unroll 4
        for (int k = 0; k < 128; k += 4) {
            float4 w0 = *(const float4*)(u0p + k);
            float4 w1 = *(const float4*)(u1p + k);
            float4 v0 = *(const float4*)(a0 + 512 + k);
            float4 v1 = *(const float4*)(a1 + 512 + k);
            float4 v2 = *(const float4*)(a2 + 512 + k);
            float4 v3 = *(const float4*)(a3 + 512 + k);
            acc0[0] += w0.x*v0.x + w0.y*v0.y + w0.z*v0.z + w0.w*v0.w;
            acc0[1] += w0.x*v1.x + w0.y*v1.y + w0.z*v1.z + w0.w*v1.w;
            acc0[2] += w0.x*v2.x + w0.y*v2.y + w0.z*v2.z + w0.w*v2.w;
            acc0[3] += w0.x*v3.x + w0.y*v3.y + w0.z*v3.z + w0.w*v3.w;
            acc1[0] += w1.x*v0.x + w1.y*v0.y + w1.z*v0.z + w1.w*v0.w;
            acc1[1] += w1.x*v1.x + w1.y*v1.y + w1.z*v1.z + w1.w*v1.w;
            acc1[2] += w1.x*v2.x + w1.y*v2.y + w1.z*v2.z + w1.w*v2.w;
            acc1[3] += w1.x*v3.x + w1.y*v3.y + w1.z*v3.z + w1.w*v3.w;
        }
    }

#pragma unroll
    for (int j = 0; j < 4; ++j) {
        gs[lr0][4 * fq + j] = acc0[j];
        gs[lr1][4 * fq + j] = acc1[j];
    }
    __syncthreads();

    for (int p = tid; p < 512; p += 256) {
        int f = p >> 5, dl = p & 31;
        float gi = gs[dl][f], gf = gs[32 + dl][f], gg = gs[64 + dl][f], go = gs[96 + dl][f];
        size_t idx = (size_t)(fbase + f) * 512 + ds * 32 + dl;
        float cc = c[idx];
        float cn = sigf(gf) * cc + sigf(gi) * tanh_f(gg);
        float hn = sigf(go) * tanh_f(cn);
        c[idx] = cn;
        h_out[idx] = hn;
    }
}

// ---------------------------------------------------------------------------
// xp GEMM: C[M][2048] = A[M][K] @ Wv[2048][K]^T + ba + bb (rev flips A rows)
// ---------------------------------------------------------------------------
__global__ void __launch_bounds__(256) gemm_xp(
    const float* __restrict__ A, int M, int K, int rev,
    const float* __restrict__ Wv, const float* __restrict__ ba, const float* __restrict__ bb,
    float* __restrict__ C)
{
    __shared__ float At[16][66];
    __shared__ float Wt[128][66];
    const int tid = threadIdx.x;
    const int nt = blockIdx.x & 15, mt = blockIdx.x >> 4;
    const int rp = tid >> 2, fq = tid & 3;
    const int lr0 = 2 * rp, lr1 = lr0 + 1;
    const int n0 = nt * 128 + lr0, n1 = n0 + 1;

    float acc0[4], acc1[4];
    {
        float b0 = ba[n0] + bb[n0], b1 = ba[n1] + bb[n1];
#pragma unroll
        for (int j = 0; j < 4; ++j) { acc0[j] = b0; acc1[j] = b1; }
    }

    for (int kt = 0; kt < K; kt += 64) {
        {
            int f = tid >> 4, c4 = tid & 15;
            int m = mt * 16 + f;
            float4 v = make_float4(0.f, 0.f, 0.f, 0.f);
            if (m < M) {
                int ar = rev ? (M - 1 - m) : m;
                v = ((const float4*)(A + (size_t)ar * K + kt))[c4];
            }
            At[f][c4 * 4 + 0] = v.x; At[f][c4 * 4 + 1] = v.y;
            At[f][c4 * 4 + 2] = v.z; At[f][c4 * 4 + 3] = v.w;
        }
        for (int i = tid; i < 2048; i += 256) {
            int lr = i >> 4, c4 = i & 15;
            float4 v = ((const float4*)(Wv + (size_t)(nt * 128 + lr) * K + kt))[c4];
            Wt[lr][c4 * 4 + 0] = v.x; Wt[lr][c4 * 4 + 1] = v.y;
            Wt[lr][c4 * 4 + 2] = v.z; Wt[lr][c4 * 4 + 3] = v.w;
        }
        __syncthreads();
        const float2* w0p = (const float2*)(&Wt[lr0][0]);
        const float2* w1p = (const float2*)(&Wt[lr1][0]);
#pragma unroll 8
        for (int kh = 0; kh < 32; ++kh) {
            float2 w0 = w0p[kh], w1 = w1p[kh];
#pragma unroll
            for (int j = 0; j < 4; ++j) {
                float2 av = ((const float2*)(&At[4 * fq + j][0]))[kh];
                acc0[j] += w0.x * av.x + w0.y * av.y;
                acc1[j] += w1.x * av.x + w1.y * av.y;
            }
        }
        __syncthreads();
    }
#pragma unroll
    for (int j = 0; j < 4; ++j) {
        int m = mt * 16 + 4 * fq + j;
        if (m < M) {
            C[(size_t)m * 2048 + n0] = acc0[j];
            C[(size_t)m * 2048 + n1] = acc1[j];
        }
    }
}

// ---------------------------------------------------------------------------
// Pyramidal bi-LSTM recurrence. grid 128 = dir(2) x blk(64); 8 dims/block.
// Whh slice (32 rows x 512) LDS-resident; 1 barrier/step, 64 arrivals/dir.
// ---------------------------------------------------------------------------
__global__ void __launch_bounds__(256) pyr_rec(
    const float* __restrict__ xpF, const float* __restrict__ xpB,
    const float* __restrict__ WhhF, const float* __restrict__ WhhB,
    float* __restrict__ hbuf,  // [buf2][dir2][512]
    float* __restrict__ outF, float* __restrict__ outB,
    int steps, int* __restrict__ barF, int* __restrict__ barB)
{
    const int tid = threadIdx.x;
    const int dir = blockIdx.x >> 6, blk = blockIdx.x & 63;
    const float* xp  = dir ? xpB : xpF;
    const float* Whh = dir ? WhhB : WhhF;
    float* outp = dir ? outB : outF;
    int* bar = dir ? barB : barF;

    __shared__ float Wl[32][516];
    __shared__ float hcur[512];
    __shared__ float red[32][9];
    __shared__ float gv[32];

    for (int i = tid; i < 4096; i += 256) {            // 32 rows x 128 float4
        int lr = i >> 7, c4 = i & 127;
        int grow = (lr >> 3) * 512 + blk * 8 + (lr & 7);
        float4 v = ((const float4*)(Whh + (size_t)grow * 512))[c4];
        *(float4*)&Wl[lr][c4 * 4] = v;
    }
    float creg = 0.f;
    const int lr = tid & 31, seg = tid >> 5;           // 32 rows x 8 segs(64k)
    __syncthreads();

    for (int t = 0; t < steps; ++t) {
        int hb = t & 1;
        for (int i = tid; i < 512; i += 256)
            hcur[i] = gld(&hbuf[(hb * 2 + dir) * 512 + i]);
        __syncthreads();

        const float* wr = &Wl[lr][seg * 64];
        const float* hr = &hcur[seg * 64];
        float a = 0.f;
#pragma unroll
        for (int k4 = 0; k4 < 16; ++k4) {
            float4 w = *(const float4*)(wr + 4 * k4);
            float4 h4 = *(const float4*)(hr + 4 * k4);
            a += w.x*h4.x + w.y*h4.y + w.z*h4.z + w.w*h4.w;
        }
        red[lr][seg] = a;
        __syncthreads();

        if (tid < 32) {
            int grow = (tid >> 3) * 512 + blk * 8 + (tid & 7);
            float g = xp[(size_t)t * 2048 + grow];
#pragma unroll
            for (int s2 = 0; s2 < 8; ++s2) g += red[tid][s2];
            gv[tid] = g;
        }
        __syncthreads();
        if (tid < 8) {
            float i_ = sigf(gv[tid]), f_ = sigf(gv[8 + tid]);
            float g_ = tanh_f(gv[16 + tid]), o_ = sigf(gv[24 + tid]);
            creg = f_ * creg + i_ * g_;
            float hn = o_ * tanh_f(creg);
            int d = blk * 8 + tid;
            gst(&hbuf[((1 - hb) * 2 + dir) * 512 + d], hn);
            int row = dir ? (steps - 1 - t) : t;
            outp[(size_t)row * 512 + d] = hn;
        }
        gbarrier(bar, 64, t + 1);
    }
}

__global__ void x2_assemble(const float* __restrict__ f1, const float* __restrict__ b1o,
                            float* __restrict__ x2)
{
    int j = blockIdx.x;
    for (int k = threadIdx.x; k < 2048; k += 256) {
        int q = k >> 9, r = k & 511;
        const float* src = (q & 1) ? b1o : f1;
        int row = 2 * j + (q >> 1);
        x2[(size_t)j * 2048 + k] = src[(size_t)row * 512 + r];
    }
}

__global__ void ctx_k(const float* __restrict__ f2, const float* __restrict__ b2o,
                      float* __restrict__ ctx, float* __restrict__ hdec, float* __restrict__ inp)
{
    int j = blockIdx.x;
    for (int k = threadIdx.x; k < 1024; k += 256)
        ctx[(size_t)j * 1024 + k] = (k < 512) ? f2[(size_t)j * 512 + k]
                                              : b2o[(size_t)j * 512 + k - 512];
    if (j == 0) {
        for (int i = threadIdx.x; i < 512; i += 256) hdec[i] = f2[59 * 512 + i];
        if (threadIdx.x < 8) inp[threadIdx.x] = (threadIdx.x == 7) ? 1.f : 0.f;
    }
}

// ---------------------------------------------------------------------------
// Decoder: 66 blocks. blocks 0/1 = attention role (ctx halves LDS-resident,
// both redundantly compute logits+softmax -> no inp dependency barrier).
// blocks 2..65 = 8 h-dims each, GRU/comb weight rows LDS-resident.
// 3 barriers/step (logits folded into next step's stage A).
// ---------------------------------------------------------------------------
__global__ void __launch_bounds__(256) dec_k(
    const float* __restrict__ attn_W, const float* __restrict__ attn_b,
    const float* __restrict__ comb_W, const float* __restrict__ comb_b,
    const float* __restrict__ gWih, const float* __restrict__ gWhh,
    const float* __restrict__ gbih, const float* __restrict__ gbhh,
    const float* __restrict__ outW, const float* __restrict__ outb,
    const float* __restrict__ ctx,
    float* __restrict__ hdec, float* __restrict__ inp,
    float* __restrict__ applied, float* __restrict__ obuf,
    float* __restrict__ dout, int* __restrict__ bar)
{
    const int tid = threadIdx.x, bid = blockIdx.x;
    __shared__ float pool[33056];
    __shared__ float hl[512];
    __shared__ float xl[1036];
    __shared__ float inpl[8];
    __shared__ float red4[60][5];
    __shared__ float red8[24][9];
    __shared__ float red32[8][33];
    __shared__ float ghl[24], gil[24];
    __shared__ float zz[60], aw[60], zd[8];
    __shared__ float ms[1];

    const bool attn_role = (bid < 2);
    float* ctxL = pool;                       // [60][516]
    float* Wg = pool;                         // [24][516]
    float* Wi = pool + 24 * 516;              // [24][516]
    float* Wc = pool + 48 * 516;              // [8][1036]
    const int dbase = (bid - 2) * 8;

    if (attn_role) {
        for (int i = tid; i < 7680; i += 256) {        // 60 x 128 float4
            int j = i >> 7, c4 = i & 127;
            float4 v = ((const float4*)(ctx + (size_t)j * 1024 + bid * 512))[c4];
            *(float4*)&ctxL[j * 516 + c4 * 4] = v;
        }
    } else {
        for (int i = tid; i < 3072; i += 256) {        // 24 x 128 float4 (x2)
            int r = i >> 7, c4 = i & 127;
            int grow = (r >> 3) * 512 + dbase + (r & 7);
            *(float4*)&Wg[r * 516 + c4 * 4] = ((const float4*)(gWhh + (size_t)grow * 512))[c4];
            *(float4*)&Wi[r * 516 + c4 * 4] = ((const float4*)(gWih + (size_t)grow * 512))[c4];
        }
        for (int i = tid; i < 2064; i += 256) {        // 8 x 258 float4
            int r = i / 258, c4 = i % 258;
            *(float4*)&Wc[r * 1036 + c4 * 4] =
                ((const float4*)(comb_W + (size_t)(dbase + r) * 1032))[c4];
        }
    }
    __syncthreads();

    int ep = 0;
    for (int s = 0; s < 30; ++s) {
        // ---------------- stage A ----------------
        for (int i = tid; i < 512; i += 256) hl[i] = gld(&hdec[i]);
        __syncthreads();
        if (attn_role) {
            if (s > 0) {   // logits of previous step (uses current h)
                {
                    int row = tid >> 5, sg = tid & 31;
                    const float* wr = outW + (size_t)row * 512 + sg * 16;
                    const float* hp = hl + sg * 16;
                    float a = 0.f;
#pragma unroll
                    for (int k = 0; k < 16; ++k) a += wr[k] * hp[k];
                    red32[row][sg] = a;
                }
                __syncthreads();
                if (tid < 8) {
                    float a = outb[tid];
#pragma unroll
                    for (int g2 = 0; g2 < 32; ++g2) a += red32[tid][g2];
                    zd[tid] = a;
                }
                __syncthreads();
                if (tid == 0) {
                    float m = zd[0];
                    for (int l = 1; l < 8; ++l) m = fmaxf(m, zd[l]);
                    float ss = 0.f;
                    for (int l = 0; l < 8; ++l) ss += __expf(zd[l] - m);
                    ms[0] = m + __logf(ss);
                }
                __syncthreads();
                if (tid < 8) {
                    float lp = zd[tid] - ms[0];
                    inpl[tid] = lp;
                    if (bid == 0) { dout[(s - 1) * 8 + tid] = lp; gst(&inp[tid], lp); }
                }
            } else {
                if (tid < 8) inpl[tid] = gld(&inp[tid]);
            }
            __syncthreads();
            {   // z = attn_W @ [inp; h] + attn_b
                int r = tid >> 2, sg = tid & 3;
                if (r < 60) {
                    int k0 = sg * 130;
                    const float* wr = attn_W + (size_t)r * 520 + k0;
                    float a = 0.f;
                    for (int k = 0; k < 130; ++k) {
                        int kk = k0 + k;
                        float x = (kk < 8) ? inpl[kk] : hl[kk - 8];
                        a += wr[k] * x;
                    }
                    red4[r][sg] = a;
                }
            }
            __syncthreads();
            if (tid < 60)
                zz[tid] = attn_b[tid] + red4[tid][0] + red4[tid][1] + red4[tid][2] + red4[tid][3];
            __syncthreads();
            if (tid == 0) {
                float m = zz[0];
                for (int j = 1; j < 60; ++j) m = fmaxf(m, zz[j]);
                float ss = 0.f;
                for (int j = 0; j < 60; ++j) { float e = __expf(zz[j] - m); aw[j] = e; ss += e; }
                float inv = 1.f / ss;
                for (int j = 0; j < 60; ++j) aw[j] *= inv;
            }
            __syncthreads();
            for (int cc = tid; cc < 512; cc += 256) {
                float a = 0.f;
                for (int j = 0; j < 60; ++j) a += aw[j] * ctxL[j * 516 + cc];
                gst(&applied[bid * 512 + cc], a);
            }
        } else {
            {   // gh = gWhh @ h (+ gbhh)
                if (tid < 192) {
                    int r = tid >> 3, sg = tid & 7;
                    const float* wr = Wg + r * 516 + sg * 64;
                    const float* hp = hl + sg * 64;
                    float a = 0.f;
#pragma unroll
                    for (int k4 = 0; k4 < 16; ++k4) {
                        float4 w = *(const float4*)(wr + 4 * k4);
                        float4 h4 = *(const float4*)(hp + 4 * k4);
                        a += w.x*h4.x + w.y*h4.y + w.z*h4.z + w.w*h4.w;
                    }
                    red8[r][sg] = a;
                }
            }
            __syncthreads();
            if (tid < 24) {
                int grow = (tid >> 3) * 512 + dbase + (tid & 7);
                float a = gbhh[grow];
#pragma unroll
                for (int g2 = 0; g2 < 8; ++g2) a += red8[tid][g2];
                ghl[tid] = a;
            }
        }
        gbarrier(bar, 66, ++ep);

        // ---------------- stage B: o = relu(comb_W @ [inp; applied]) ----------------
        if (!attn_role) {
            if (tid < 8) xl[tid] = gld(&inp[tid]);
            for (int i = tid; i < 1024; i += 256) xl[8 + i] = gld(&applied[i]);
            __syncthreads();
            {
                int row = tid >> 5, sg = tid & 31;
                const float* wr = Wc + row * 1036;
                float a = 0.f;
                for (int k = sg; k < 1032; k += 32) a += wr[k] * xl[k];
                red32[row][sg] = a;
            }
            __syncthreads();
            if (tid < 8) {
                float a = comb_b[dbase + tid];
#pragma unroll
                for (int g2 = 0; g2 < 32; ++g2) a += red32[tid][g2];
                gst(&obuf[dbase + tid], fmaxf(a, 0.f));
            }
        }
        gbarrier(bar, 66, ++ep);

        // ---------------- stage C: gi + GRU combine ----------------
        if (!attn_role) {
            for (int i = tid; i < 512; i += 256) xl[i] = gld(&obuf[i]);
            __syncthreads();
            {
                if (tid < 192) {
                    int r = tid >> 3, sg = tid & 7;
                    const float* wr = Wi + r * 516 + sg * 64;
                    const float* op = xl + sg * 64;
                    float a = 0.f;
#pragma unroll
                    for (int k4 = 0; k4 < 16; ++k4) {
                        float4 w = *(const float4*)(wr + 4 * k4);
                        float4 o4 = *(const float4*)(op + 4 * k4);
                        a += w.x*o4.x + w.y*o4.y + w.z*o4.z + w.w*o4.w;
                    }
                    red8[r][sg] = a;
                }
            }
            __syncthreads();
            if (tid < 24) {
                int grow = (tid >> 3) * 512 + dbase + (tid & 7);
                float a = gbih[grow];
#pragma unroll
                for (int g2 = 0; g2 < 8; ++g2) a += red8[tid][g2];
                gil[tid] = a;
            }
            __syncthreads();
            if (tid < 8) {
                float r_ = sigf(gil[tid] + ghl[tid]);
                float z_ = sigf(gil[8 + tid] + ghl[8 + tid]);
                float n_ = tanh_f(gil[16 + tid] + r_ * ghl[16 + tid]);
                float hnew = (1.f - z_) * n_ + z_ * hl[dbase + tid];
                gst(&hdec[dbase + tid], hnew);
            }
        }
        gbarrier(bar, 66, ++ep);
    }

    // epilogue: logits for s=29
    if (bid == 0) {
        for (int i = tid; i < 512; i += 256) hl[i] = gld(&hdec[i]);
        __syncthreads();
        {
            int row = tid >> 5, sg = tid & 31;
            const float* wr = outW + (size_t)row * 512 + sg * 16;
            const float* hp = hl + sg * 16;
            float a = 0.f;
#pragma unroll
            for (int k = 0; k < 16; ++k) a += wr[k] * hp[k];
            red32[row][sg] = a;
        }
        __syncthreads();
        if (tid < 8) {
            float a = outb[tid];
#pragma unroll
            for (int g2 = 0; g2 < 32; ++g2) a += red32[tid][g2];
            zd[tid] = a;
        }
        __syncthreads();
        if (tid == 0) {
            float m = zd[0];
            for (int l = 1; l < 8; ++l) m = fmaxf(m, zd[l]);
            float ss = 0.f;
            for (int l = 0; l < 8; ++l) ss += __expf(zd[l] - m);
            ms[0] = m + __logf(ss);
        }
        __syncthreads();
        if (tid < 8) dout[29 * 8 + tid] = zd[tid] - ms[0];
    }
}

// ---------------------------------------------------------------------------
extern "C" void kernel_launch(void* const* d_in, const int* in_sizes, int n_in,
                              void* d_out, int out_size, void* d_ws, size_t ws_size,
                              hipStream_t stream) {
    (void)in_sizes; (void)n_in; (void)out_size; (void)ws_size;
    const float* data    = (const float*)d_in[0];
    const float* enc_Wih = (const float*)d_in[1];
    const float* enc_Whh = (const float*)d_in[2];
    const float* enc_bih = (const float*)d_in[3];
    const float* enc_bhh = (const float*)d_in[4];
    const float* p1f_Wih = (const float*)d_in[5];
    const float* p1f_Whh = (const float*)d_in[6];
    const float* p1f_bih = (const float*)d_in[7];
    const float* p1f_bhh = (const float*)d_in[8];
    const float* p1b_Wih = (const float*)d_in[9];
    const float* p1b_Whh = (const float*)d_in[10];
    const float* p1b_bih = (const float*)d_in[11];
    const float* p1b_bhh = (const float*)d_in[12];
    const float* p2f_Wih = (const float*)d_in[13];
    const float* p2f_Whh = (const float*)d_in[14];
    const float* p2f_bih = (const float*)d_in[15];
    const float* p2f_bhh = (const float*)d_in[16];
    const float* p2b_Wih = (const float*)d_in[17];
    const float* p2b_Whh = (const float*)d_in[18];
    const float* p2b_bih = (const float*)d_in[19];
    const float* p2b_bhh = (const float*)d_in[20];
    const float* attn_W  = (const float*)d_in[21];
    const float* attn_b  = (const float*)d_in[22];
    const float* comb_W  = (const float*)d_in[23];
    const float* comb_b  = (const float*)d_in[24];
    const float* gru_Wih = (const float*)d_in[25];
    const float* gru_Whh = (const float*)d_in[26];
    const float* gru_bih = (const float*)d_in[27];
    const float* gru_bhh = (const float*)d_in[28];
    const float* out_W   = (const float*)d_in[29];
    const float* out_b   = (const float*)d_in[30];

    float* ws = (float*)d_ws;
    float* hb0   = ws;                  // 122880
    float* cenc  = ws + 122880;         // 122880
    float* ph1   = ws + 245760;         // 2048
    float* ph2   = ws + 247808;         // 2048
    int*   bars  = (int*)(ws + 249856); // 256 ints
    float* hb1   = ws + 250112;         // 122880
    float* xp1f  = ws + 372992;         // 245760
    float* xp1b  = ws + 618752;         // 245760
    float* f1    = ws + 864512;         // 61440
    float* b1o   = ws + 925952;         // 61440
    float* x2    = ws + 987392;         // 122880
    float* xp2f  = ws + 1110272;        // 122880
    float* xp2b  = ws + 1233152;        // 122880
    float* f2    = ws + 1356032;        // 30720
    float* b2o   = ws + 1386752;        // 30720
    float* ctxb  = ws + 1417472;        // 61440
    float* hdec  = ws + 1478912;        // 512
    float* inp   = ws + 1479424;        // 16
    float* appl  = ws + 1479440;        // 1024
    float* obuf  = ws + 1480464;        // 512

    init_k<<<256, 256, 0, stream>>>(ws);

    float* hbs[2] = {hb0, hb1};
    for (int t = 0; t < 64; ++t)
        enc_step<<<240, 256, 0, stream>>>(t, data, enc_Wih, enc_Whh, enc_bih, enc_bhh,
                                          hbs[t & 1], hbs[(t + 1) & 1], cenc);
    gemm_xp<<<128, 256, 0, stream>>>(hb0, 120, 1024, 0, p1f_Wih, p1f_bih, p1f_bhh, xp1f);
    gemm_xp<<<128, 256, 0, stream>>>(hb0, 120, 1024, 1, p1b_Wih, p1b_bih, p1b_bhh, xp1b);
    pyr_rec<<<128, 256, 0, stream>>>(xp1f, xp1b, p1f_Whh, p1b_Whh, ph1, f1, b1o, 120,
                                     bars + 0, bars + 32);
    x2_assemble<<<60, 256, 0, stream>>>(f1, b1o, x2);
    gemm_xp<<<64, 256, 0, stream>>>(x2, 60, 2048, 0, p2f_Wih, p2f_bih, p2f_bhh, xp2f);
    gemm_xp<<<64, 256, 0, stream>>>(x2, 60, 2048, 1, p2b_Wih, p2b_bih, p2b_bhh, xp2b);
    pyr_rec<<<128, 256, 0, stream>>>(xp2f, xp2b, p2f_Whh, p2b_Whh, ph2, f2, b2o, 60,
                                     bars + 64, bars + 96);
    ctx_k<<<60, 256, 0, stream>>>(f2, b2o, ctxb, hdec, inp);
    dec_k<<<66, 256, 0, stream>>>(attn_W, attn_b, comb_W, comb_b,
                                  gru_Wih, gru_Whh, gru_bih, gru_bhh,
                                  out_W, out_b, ctxb, hdec, inp, appl, obuf,
                                  (float*)d_out, bars + 128);
}

// Round 3
// 4393.950 us; speedup vs baseline: 1.6496x; 1.0374x over previous
//
#include <hip/hip_runtime.h>
#include <math.h>

// Model dims: H=512 D=128 L=8 T=64 W=240 CTX=60 NSTEPS=30

__device__ __forceinline__ float sigf(float x) { return 1.f / (1.f + __expf(-x)); }
__device__ __forceinline__ float tanh_f(float x) {
    float e = __expf(2.f * x);
    return 1.f - 2.f / (e + 1.f);
}

__device__ __forceinline__ float gld(const float* p) {
    return __hip_atomic_load(p, __ATOMIC_RELAXED, __HIP_MEMORY_SCOPE_AGENT);
}
__device__ __forceinline__ void gst(float* p, float v) {
    __hip_atomic_store(p, v, __ATOMIC_RELAXED, __HIP_MEMORY_SCOPE_AGENT);
}
// Distributed epoch flags: one cache line (32 ints) per producer block.
__device__ __forceinline__ void set_flag(int* f, int v) {
    __hip_atomic_store(f, v, __ATOMIC_RELEASE, __HIP_MEMORY_SCOPE_AGENT);
}
__device__ __forceinline__ void wait_flag_ge(int* f, int ep) {
    while (__hip_atomic_load(f, __ATOMIC_ACQUIRE, __HIP_MEMORY_SCOPE_AGENT) < ep)
        __builtin_amdgcn_s_sleep(1);
}

// ---------------------------------------------------------------------------
// init: zero [hbufE | ph1 | ph2 | all flag arrays] = 269888 floats
// ---------------------------------------------------------------------------
__global__ void init_k(float* __restrict__ ws) {
    for (int i = blockIdx.x * blockDim.x + threadIdx.x; i < 269888; i += gridDim.x * blockDim.x)
        ws[i] = 0.f;
}

// ---------------------------------------------------------------------------
// Encoder, ONE persistent launch, 64 steps. grid 240 = fg(15)*ds(16).
// Group = 16 blocks sharing fg; per-step sync only within group (epoch flags).
// Block: 128 gate rows (32 dims) x 16 frames, K=640. c-state in LDS.
// ---------------------------------------------------------------------------
__global__ void __launch_bounds__(256) enc_all(
    const float* __restrict__ data,
    const float* __restrict__ Wih, const float* __restrict__ Whh,
    const float* __restrict__ bih, const float* __restrict__ bhh,
    float* __restrict__ hbuf,      // [2][240][512]
    int* __restrict__ flags)       // [240][32]
{
    __shared__ float act[16][652];   // [frame][k]; k<512 = h, k>=512 = x
    __shared__ float gs[128][17];    // gate results [row][frame]
    __shared__ float cs[512];        // c state [frame*32+dim]

    const int tid = threadIdx.x;
    const int fg = blockIdx.x >> 4, ds = blockIdx.x & 15;
    const int fbase = fg * 16;

    for (int i = tid; i < 512; i += 256) cs[i] = 0.f;

    const int rp = tid >> 2, fq = tid & 3;
    const int lr0 = 2 * rp, lr1 = lr0 + 1;
    const int grow0 = (lr0 >> 5) * 512 + ds * 32 + (lr0 & 31);
    const int grow1 = (lr1 >> 5) * 512 + ds * 32 + (lr1 & 31);
    const float bias0 = bih[grow0] + bhh[grow0];
    const float bias1 = bih[grow1] + bhh[grow1];
    const float* w0p = Whh + (size_t)grow0 * 512;
    const float* w1p = Whh + (size_t)grow1 * 512;
    const float* u0p = Wih + (size_t)grow0 * 128;
    const float* u1p = Wih + (size_t)grow1 * 128;
    const float* a0 = &act[4 * fq + 0][0];
    const float* a1 = &act[4 * fq + 1][0];
    const float* a2 = &act[4 * fq + 2][0];
    const float* a3 = &act[4 * fq + 3][0];

    for (int t = 0; t < 64; ++t) {
        if (t > 0) {
            if (tid < 16) wait_flag_ge(&flags[(fg * 16 + tid) * 32], t);
        }
        __syncthreads();
        // stage h (group-shared, epoch t) and x_t
        const float* hin = hbuf + (size_t)((t & 1) * 240 + fbase) * 512;
        for (int i = tid; i < 8192; i += 256)
            act[i >> 9][i & 511] = gld(hin + i);
        for (int i = tid; i < 512; i += 256) {
            int f = i >> 5, c4 = i & 31;
            float4 v = ((const float4*)(data + ((size_t)t * 240 + fbase + f) * 128))[c4];
            *(float4*)&act[f][512 + c4 * 4] = v;
        }
        __syncthreads();

        float acc0[4], acc1[4];
#pragma unroll
        for (int j = 0; j < 4; ++j) { acc0[j] = bias0; acc1[j] = bias1; }

#pragma unroll 4
        for (int k = 0; k < 512; k += 4) {
            float4 w0 = *(const float4*)(w0p + k);
            float4 w1 = *(const float4*)(w1p + k);
            float4 v0 = *(const float4*)(a0 + k);
            float4 v1 = *(const float4*)(a1 + k);
            float4 v2 = *(const float4*)(a2 + k);
            float4 v3 = *(const float4*)(a3 + k);
            acc0[0] += w0.x*v0.x + w0.y*v0.y + w0.z*v0.z + w0.w*v0.w;
            acc0[1] += w0.x*v1.x + w0.y*v1.y + w0.z*v1.z + w0.w*v1.w;
            acc0[2] += w0.x*v2.x + w0.y*v2.y + w0.z*v2.z + w0.w*v2.w;
            acc0[3] += w0.x*v3.x + w0.y*v3.y + w0.z*v3.z + w0.w*v3.w;
            acc1[0] += w1.x*v0.x + w1.y*v0.y + w1.z*v0.z + w1.w*v0.w;
            acc1[1] += w1.x*v1.x + w1.y*v1.y + w1.z*v1.z + w1.w*v1.w;
            acc1[2] += w1.x*v2.x + w1.y*v2.y + w1.z*v2.z + w1.w*v2.w;
            acc1[3] += w1.x*v3.x + w1.y*v3.y + w1.z*v3.z + w1.w*v3.w;
        }
#pragma unroll 4
        for (int k = 0; k < 128; k += 4) {
            float4 w0 = *(const float4*)(u0p + k);
            float4 w1 = *(const float4*)(u1p + k);
            float4 v0 = *(const float4*)(a0 + 512 + k);
            float4 v1 = *(const float4*)(a1 + 512 + k);
            float4 v2 = *(const float4*)(a2 + 512 + k);
            float4 v3 = *(const float4*)(a3 + 512 + k);
            acc0[0] += w0.x*v0.x + w0.y*v0.y + w0.z*v0.z + w0.w*v0.w;
            acc0[1] += w0.x*v1.x + w0.y*v1.y + w0.z*v1.z + w0.w*v1.w;
            acc0[2] += w0.x*v2.x + w0.y*v2.y + w0.z*v2.z + w0.w*v2.w;
            acc0[3] += w0.x*v3.x + w0.y*v3.y + w0.z*v3.z + w0.w*v3.w;
            acc1[0] += w1.x*v0.x + w1.y*v0.y + w1.z*v0.z + w1.w*v0.w;
            acc1[1] += w1.x*v1.x + w1.y*v1.y + w1.z*v1.z + w1.w*v1.w;
            acc1[2] += w1.x*v2.x + w1.y*v2.y + w1.z*v2.z + w1.w*v2.w;
            acc1[3] += w1.x*v3.x + w1.y*v3.y + w1.z*v3.z + w1.w*v3.w;
        }

#pragma unroll
        for (int j = 0; j < 4; ++j) {
            gs[lr0][4 * fq + j] = acc0[j];
            gs[lr1][4 * fq + j] = acc1[j];
        }
        __syncthreads();

        float* hnext = hbuf + (size_t)(((t + 1) & 1) * 240) * 512;
        for (int p = tid; p < 512; p += 256) {
            int f = p >> 5, dl = p & 31;
            float gi = gs[dl][f], gf = gs[32 + dl][f], gg = gs[64 + dl][f], go = gs[96 + dl][f];
            float cc = cs[p];
            float cn = sigf(gf) * cc + sigf(gi) * tanh_f(gg);
            float hn = sigf(go) * tanh_f(cn);
            cs[p] = cn;
            gst(&hnext[(size_t)(fbase + f) * 512 + ds * 32 + dl], hn);
        }
        __syncthreads();
        if (tid == 0) set_flag(&flags[(fg * 16 + ds) * 32], t + 1);
    }
}

// ---------------------------------------------------------------------------
// xp GEMM: C[M][2048] = A[M][K] @ Wv[2048][K]^T + ba + bb (rev flips A rows)
// ---------------------------------------------------------------------------
__global__ void __launch_bounds__(256) gemm_xp(
    const float* __restrict__ A, int M, int K, int rev,
    const float* __restrict__ Wv, const float* __restrict__ ba, const float* __restrict__ bb,
    float* __restrict__ C)
{
    __shared__ float At[16][66];
    __shared__ float Wt[128][66];
    const int tid = threadIdx.x;
    const int nt = blockIdx.x & 15, mt = blockIdx.x >> 4;
    const int rp = tid >> 2, fq = tid & 3;
    const int lr0 = 2 * rp, lr1 = lr0 + 1;
    const int n0 = nt * 128 + lr0, n1 = n0 + 1;

    float acc0[4], acc1[4];
    {
        float b0 = ba[n0] + bb[n0], b1 = ba[n1] + bb[n1];
#pragma unroll
        for (int j = 0; j < 4; ++j) { acc0[j] = b0; acc1[j] = b1; }
    }

    for (int kt = 0; kt < K; kt += 64) {
        {
            int f = tid >> 4, c4 = tid & 15;
            int m = mt * 16 + f;
            float4 v = make_float4(0.f, 0.f, 0.f, 0.f);
            if (m < M) {
                int ar = rev ? (M - 1 - m) : m;
                v = ((const float4*)(A + (size_t)ar * K + kt))[c4];
            }
            At[f][c4 * 4 + 0] = v.x; At[f][c4 * 4 + 1] = v.y;
            At[f][c4 * 4 + 2] = v.z; At[f][c4 * 4 + 3] = v.w;
        }
        for (int i = tid; i < 2048; i += 256) {
            int lr = i >> 4, c4 = i & 15;
            float4 v = ((const float4*)(Wv + (size_t)(nt * 128 + lr) * K + kt))[c4];
            Wt[lr][c4 * 4 + 0] = v.x; Wt[lr][c4 * 4 + 1] = v.y;
            Wt[lr][c4 * 4 + 2] = v.z; Wt[lr][c4 * 4 + 3] = v.w;
        }
        __syncthreads();
        const float2* w0p = (const float2*)(&Wt[lr0][0]);
        const float2* w1p = (const float2*)(&Wt[lr1][0]);
#pragma unroll 8
        for (int kh = 0; kh < 32; ++kh) {
            float2 w0 = w0p[kh], w1 = w1p[kh];
#pragma unroll
            for (int j = 0; j < 4; ++j) {
                float2 av = ((const float2*)(&At[4 * fq + j][0]))[kh];
                acc0[j] += w0.x * av.x + w0.y * av.y;
                acc1[j] += w1.x * av.x + w1.y * av.y;
            }
        }
        __syncthreads();
    }
#pragma unroll
    for (int j = 0; j < 4; ++j) {
        int m = mt * 16 + 4 * fq + j;
        if (m < M) {
            C[(size_t)m * 2048 + n0] = acc0[j];
            C[(size_t)m * 2048 + n1] = acc1[j];
        }
    }
}

// ---------------------------------------------------------------------------
// Pyramidal bi-LSTM recurrence. grid 128 = dir(2) x blk(64); 8 dims/block.
// Whh slice LDS-resident; per-step sync via distributed epoch flags.
// ---------------------------------------------------------------------------
__global__ void __launch_bounds__(256) pyr_rec(
    const float* __restrict__ xpF, const float* __restrict__ xpB,
    const float* __restrict__ WhhF, const float* __restrict__ WhhB,
    float* __restrict__ hbuf,  // [buf2][dir2][512]
    float* __restrict__ outF, float* __restrict__ outB,
    int steps, int* __restrict__ flagF, int* __restrict__ flagB)
{
    const int tid = threadIdx.x;
    const int dir = blockIdx.x >> 6, blk = blockIdx.x & 63;
    const float* xp  = dir ? xpB : xpF;
    const float* Whh = dir ? WhhB : WhhF;
    float* outp = dir ? outB : outF;
    int* flag = dir ? flagB : flagF;

    __shared__ float Wl[32][516];
    __shared__ float hcur[512];
    __shared__ float red[32][9];
    __shared__ float gv[32];

    for (int i = tid; i < 4096; i += 256) {            // 32 rows x 128 float4
        int lr = i >> 7, c4 = i & 127;
        int grow = (lr >> 3) * 512 + blk * 8 + (lr & 7);
        float4 v = ((const float4*)(Whh + (size_t)grow * 512))[c4];
        *(float4*)&Wl[lr][c4 * 4] = v;
    }
    float creg = 0.f;
    const int lr = tid & 31, seg = tid >> 5;
    __syncthreads();

    for (int t = 0; t < steps; ++t) {
        if (t > 0) {
            if (tid < 64) wait_flag_ge(&flag[tid * 32], t);
        }
        __syncthreads();
        int hb = t & 1;
        for (int i = tid; i < 512; i += 256)
            hcur[i] = gld(&hbuf[(hb * 2 + dir) * 512 + i]);
        __syncthreads();

        const float* wr = &Wl[lr][seg * 64];
        const float* hr = &hcur[seg * 64];
        float a = 0.f;
#pragma unroll
        for (int k4 = 0; k4 < 16; ++k4) {
            float4 w = *(const float4*)(wr + 4 * k4);
            float4 h4 = *(const float4*)(hr + 4 * k4);
            a += w.x*h4.x + w.y*h4.y + w.z*h4.z + w.w*h4.w;
        }
        red[lr][seg] = a;
        __syncthreads();

        if (tid < 32) {
            int grow = (tid >> 3) * 512 + blk * 8 + (tid & 7);
            float g = xp[(size_t)t * 2048 + grow];
#pragma unroll
            for (int s2 = 0; s2 < 8; ++s2) g += red[tid][s2];
            gv[tid] = g;
        }
        __syncthreads();
        if (tid < 8) {
            float i_ = sigf(gv[tid]), f_ = sigf(gv[8 + tid]);
            float g_ = tanh_f(gv[16 + tid]), o_ = sigf(gv[24 + tid]);
            creg = f_ * creg + i_ * g_;
            float hn = o_ * tanh_f(creg);
            int d = blk * 8 + tid;
            gst(&hbuf[((1 - hb) * 2 + dir) * 512 + d], hn);
            int row = dir ? (steps - 1 - t) : t;
            outp[(size_t)row * 512 + d] = hn;
        }
        __syncthreads();
        if (tid == 0) set_flag(&flag[blk * 32], t + 1);
    }
}

__global__ void x2_assemble(const float* __restrict__ f1, const float* __restrict__ b1o,
                            float* __restrict__ x2)
{
    int j = blockIdx.x;
    for (int k = threadIdx.x; k < 2048; k += 256) {
        int q = k >> 9, r = k & 511;
        const float* src = (q & 1) ? b1o : f1;
        int row = 2 * j + (q >> 1);
        x2[(size_t)j * 2048 + k] = src[(size_t)row * 512 + r];
    }
}

__global__ void ctx_k(const float* __restrict__ f2, const float* __restrict__ b2o,
                      float* __restrict__ ctx, float* __restrict__ hdec, float* __restrict__ inp)
{
    int j = blockIdx.x;
    for (int k = threadIdx.x; k < 1024; k += 256)
        ctx[(size_t)j * 1024 + k] = (k < 512) ? f2[(size_t)j * 512 + k]
                                              : b2o[(size_t)j * 512 + k - 512];
    if (j == 0) {
        for (int i = threadIdx.x; i < 512; i += 256) hdec[i] = f2[59 * 512 + i];
        if (threadIdx.x < 8) inp[threadIdx.x] = (threadIdx.x == 7) ? 1.f : 0.f;
    }
}

// ---------------------------------------------------------------------------
// Decoder: 66 blocks. blocks 0/1 = attention (ctx halves LDS-resident, both
// compute logits redundantly); blocks 2..65 = 8 h-dims each (GRU/comb weights
// LDS-resident). Dependency-shaped epoch flags: stage B waits on only the 2
// attention flags; obuf/hdec flags polled in parallel by 64 threads.
// ---------------------------------------------------------------------------
__global__ void __launch_bounds__(256) dec_k(
    const float* __restrict__ attn_W, const float* __restrict__ attn_b,
    const float* __restrict__ comb_W, const float* __restrict__ comb_b,
    const float* __restrict__ gWih, const float* __restrict__ gWhh,
    const float* __restrict__ gbih, const float* __restrict__ gbhh,
    const float* __restrict__ outW, const float* __restrict__ outb,
    const float* __restrict__ ctx,
    float* __restrict__ hdec, float* __restrict__ inp,
    float* __restrict__ applied, float* __restrict__ obuf,
    float* __restrict__ dout,
    int* __restrict__ flagA, int* __restrict__ flagB, int* __restrict__ flagC)
{
    const int tid = threadIdx.x, bid = blockIdx.x;
    __shared__ float pool[33056];
    __shared__ float hl[512];
    __shared__ float xl[1036];
    __shared__ float inpl[8];
    __shared__ float red4[60][5];
    __shared__ float red8[24][9];
    __shared__ float red32[8][33];
    __shared__ float ghl[24], gil[24];
    __shared__ float zz[60], aw[60], zd[8];
    __shared__ float ms[1];

    const bool attn_role = (bid < 2);
    float* ctxL = pool;                       // [60][516]
    float* Wg = pool;                         // [24][516]
    float* Wi = pool + 24 * 516;              // [24][516]
    float* Wc = pool + 48 * 516;              // [8][1036]
    const int gbid = bid - 2;
    const int dbase = gbid * 8;

    if (attn_role) {
        for (int i = tid; i < 7680; i += 256) {        // 60 x 128 float4
            int j = i >> 7, c4 = i & 127;
            float4 v = ((const float4*)(ctx + (size_t)j * 1024 + bid * 512))[c4];
            *(float4*)&ctxL[j * 516 + c4 * 4] = v;
        }
    } else {
        for (int i = tid; i < 3072; i += 256) {        // 24 x 128 float4 (x2)
            int r = i >> 7, c4 = i & 127;
            int grow = (r >> 3) * 512 + dbase + (r & 7);
            *(float4*)&Wg[r * 516 + c4 * 4] = ((const float4*)(gWhh + (size_t)grow * 512))[c4];
            *(float4*)&Wi[r * 516 + c4 * 4] = ((const float4*)(gWih + (size_t)grow * 512))[c4];
        }
        for (int i = tid; i < 2064; i += 256) {        // 8 x 258 float4
            int r = i / 258, c4 = i % 258;
            *(float4*)&Wc[r * 1036 + c4 * 4] =
                ((const float4*)(comb_W + (size_t)(dbase + r) * 1032))[c4];
        }
    }
    __syncthreads();

    for (int s = 0; s < 30; ++s) {
        if (s > 0) {
            if (tid < 64) wait_flag_ge(&flagC[tid * 32], s);
        }
        __syncthreads();
        for (int i = tid; i < 512; i += 256) hl[i] = gld(&hdec[i]);
        __syncthreads();

        if (attn_role) {
            if (s > 0) {   // logits of previous step (uses current h)
                {
                    int row = tid >> 5, sg = tid & 31;
                    const float* wr = outW + (size_t)row * 512 + sg * 16;
                    const float* hp = hl + sg * 16;
                    float a = 0.f;
#pragma unroll
                    for (int k = 0; k < 16; ++k) a += wr[k] * hp[k];
                    red32[row][sg] = a;
                }
                __syncthreads();
                if (tid < 8) {
                    float a = outb[tid];
#pragma unroll
                    for (int g2 = 0; g2 < 32; ++g2) a += red32[tid][g2];
                    zd[tid] = a;
                }
                __syncthreads();
                if (tid == 0) {
                    float m = zd[0];
                    for (int l = 1; l < 8; ++l) m = fmaxf(m, zd[l]);
                    float ss = 0.f;
                    for (int l = 0; l < 8; ++l) ss += __expf(zd[l] - m);
                    ms[0] = m + __logf(ss);
                }
                __syncthreads();
                if (tid < 8) {
                    float lp = zd[tid] - ms[0];
                    inpl[tid] = lp;
                    if (bid == 0) { dout[(s - 1) * 8 + tid] = lp; gst(&inp[tid], lp); }
                }
            } else {
                if (tid < 8) inpl[tid] = gld(&inp[tid]);
            }
            __syncthreads();
            {   // z = attn_W @ [inp; h] + attn_b
                int r = tid >> 2, sg = tid & 3;
                if (r < 60) {
                    int k0 = sg * 130;
                    const float* wr = attn_W + (size_t)r * 520 + k0;
                    float a = 0.f;
                    for (int k = 0; k < 130; ++k) {
                        int kk = k0 + k;
                        float x = (kk < 8) ? inpl[kk] : hl[kk - 8];
                        a += wr[k] * x;
                    }
                    red4[r][sg] = a;
                }
            }
            __syncthreads();
            if (tid < 60)
                zz[tid] = attn_b[tid] + red4[tid][0] + red4[tid][1] + red4[tid][2] + red4[tid][3];
            __syncthreads();
            if (tid == 0) {
                float m = zz[0];
                for (int j = 1; j < 60; ++j) m = fmaxf(m, zz[j]);
                float ss = 0.f;
                for (int j = 0; j < 60; ++j) { float e = __expf(zz[j] - m); aw[j] = e; ss += e; }
                float inv = 1.f / ss;
                for (int j = 0; j < 60; ++j) aw[j] *= inv;
            }
            __syncthreads();
            for (int cc = tid; cc < 512; cc += 256) {
                float a = 0.f;
                for (int j = 0; j < 60; ++j) a += aw[j] * ctxL[j * 516 + cc];
                gst(&applied[bid * 512 + cc], a);
            }
            __syncthreads();
            if (tid == 0) set_flag(&flagA[bid * 32], s + 1);
        } else {
            {   // gh = gWhh @ h (+ gbhh) — no cross-block dependency
                if (tid < 192) {
                    int r = tid >> 3, sg = tid & 7;
                    const float* wr = Wg + r * 516 + sg * 64;
                    const float* hp = hl + sg * 64;
                    float a = 0.f;
#pragma unroll
                    for (int k4 = 0; k4 < 16; ++k4) {
                        float4 w = *(const float4*)(wr + 4 * k4);
                        float4 h4 = *(const float4*)(hp + 4 * k4);
                        a += w.x*h4.x + w.y*h4.y + w.z*h4.z + w.w*h4.w;
                    }
                    red8[r][sg] = a;
                }
            }
            __syncthreads();
            if (tid < 24) {
                int grow = (tid >> 3) * 512 + dbase + (tid & 7);
                float a = gbhh[grow];
#pragma unroll
                for (int g2 = 0; g2 < 8; ++g2) a += red8[tid][g2];
                ghl[tid] = a;
            }
            // ---- wait applied + inp (2 producer flags) ----
            if (tid < 2) wait_flag_ge(&flagA[tid * 32], s + 1);
            __syncthreads();
            if (tid < 8) xl[tid] = gld(&inp[tid]);
            for (int i = tid; i < 1024; i += 256) xl[8 + i] = gld(&applied[i]);
            __syncthreads();
            {   // stage B: o = relu(comb_W @ [inp; applied])
                int row = tid >> 5, sg = tid & 31;
                const float* wr = Wc + row * 1036;
                float a = 0.f;
                for (int k = sg; k < 1032; k += 32) a += wr[k] * xl[k];
                red32[row][sg] = a;
            }
            __syncthreads();
            if (tid < 8) {
                float a = comb_b[dbase + tid];
#pragma unroll
                for (int g2 = 0; g2 < 32; ++g2) a += red32[tid][g2];
                gst(&obuf[dbase + tid], fmaxf(a, 0.f));
            }
            __syncthreads();
            if (tid == 0) set_flag(&flagB[gbid * 32], s + 1);
            if (tid < 64) wait_flag_ge(&flagB[tid * 32], s + 1);
            __syncthreads();
            for (int i = tid; i < 512; i += 256) xl[i] = gld(&obuf[i]);
            __syncthreads();
            {   // stage C: gi = gWih @ o
                if (tid < 192) {
                    int r = tid >> 3, sg = tid & 7;
                    const float* wr = Wi + r * 516 + sg * 64;
                    const float* op = xl + sg * 64;
                    float a = 0.f;
#pragma unroll
                    for (int k4 = 0; k4 < 16; ++k4) {
                        float4 w = *(const float4*)(wr + 4 * k4);
                        float4 o4 = *(const float4*)(op + 4 * k4);
                        a += w.x*o4.x + w.y*o4.y + w.z*o4.z + w.w*o4.w;
                    }
                    red8[r][sg] = a;
                }
            }
            __syncthreads();
            if (tid < 24) {
                int grow = (tid >> 3) * 512 + dbase + (tid & 7);
                float a = gbih[grow];
#pragma unroll
                for (int g2 = 0; g2 < 8; ++g2) a += red8[tid][g2];
                gil[tid] = a;
            }
            __syncthreads();
            if (tid < 8) {
                float r_ = sigf(gil[tid] + ghl[tid]);
                float z_ = sigf(gil[8 + tid] + ghl[8 + tid]);
                float n_ = tanh_f(gil[16 + tid] + r_ * ghl[16 + tid]);
                float hnew = (1.f - z_) * n_ + z_ * hl[dbase + tid];
                gst(&hdec[dbase + tid], hnew);
            }
            __syncthreads();
            if (tid == 0) set_flag(&flagC[gbid * 32], s + 1);
        }
    }

    // epilogue: logits for s=29
    if (bid == 0) {
        if (tid < 64) wait_flag_ge(&flagC[tid * 32], 30);
        __syncthreads();
        for (int i = tid; i < 512; i += 256) hl[i] = gld(&hdec[i]);
        __syncthreads();
        {
            int row = tid >> 5, sg = tid & 31;
            const float* wr = outW + (size_t)row * 512 + sg * 16;
            const float* hp = hl + sg * 16;
            float a = 0.f;
#pragma unroll
            for (int k = 0; k < 16; ++k) a += wr[k] * hp[k];
            red32[row][sg] = a;
        }
        __syncthreads();
        if (tid < 8) {
            float a = outb[tid];
#pragma unroll
            for (int g2 = 0; g2 < 32; ++g2) a += red32[tid][g2];
            zd[tid] = a;
        }
        __syncthreads();
        if (tid == 0) {
            float m = zd[0];
            for (int l = 1; l < 8; ++l) m = fmaxf(m, zd[l]);
            float ss = 0.f;
            for (int l = 0; l < 8; ++l) ss += __expf(zd[l] - m);
            ms[0] = m + __logf(ss);
        }
        __syncthreads();
        if (tid < 8) dout[29 * 8 + tid] = zd[tid] - ms[0];
    }
}

// ---------------------------------------------------------------------------
extern "C" void kernel_launch(void* const* d_in, const int* in_sizes, int n_in,
                              void* d_out, int out_size, void* d_ws, size_t ws_size,
                              hipStream_t stream) {
    (void)in_sizes; (void)n_in; (void)out_size; (void)ws_size;
    const float* data    = (const float*)d_in[0];
    const float* enc_Wih = (const float*)d_in[1];
    const float* enc_Whh = (const float*)d_in[2];
    const float* enc_bih = (const float*)d_in[3];
    const float* enc_bhh = (const float*)d_in[4];
    const float* p1f_Wih = (const float*)d_in[5];
    const float* p1f_Whh = (const float*)d_in[6];
    const float* p1f_bih = (const float*)d_in[7];
    const float* p1f_bhh = (const float*)d_in[8];
    const float* p1b_Wih = (const float*)d_in[9];
    const float* p1b_Whh = (const float*)d_in[10];
    const float* p1b_bih = (const float*)d_in[11];
    const float* p1b_bhh = (const float*)d_in[12];
    const float* p2f_Wih = (const float*)d_in[13];
    const float* p2f_Whh = (const float*)d_in[14];
    const float* p2f_bih = (const float*)d_in[15];
    const float* p2f_bhh = (const float*)d_in[16];
    const float* p2b_Wih = (const float*)d_in[17];
    const float* p2b_Whh = (const float*)d_in[18];
    const float* p2b_bih = (const float*)d_in[19];
    const float* p2b_bhh = (const float*)d_in[20];
    const float* attn_W  = (const float*)d_in[21];
    const float* attn_b  = (const float*)d_in[22];
    const float* comb_W  = (const float*)d_in[23];
    const float* comb_b  = (const float*)d_in[24];
    const float* gru_Wih = (const float*)d_in[25];
    const float* gru_Whh = (const float*)d_in[26];
    const float* gru_bih = (const float*)d_in[27];
    const float* gru_bhh = (const float*)d_in[28];
    const float* out_W   = (const float*)d_in[29];
    const float* out_b   = (const float*)d_in[30];

    float* ws = (float*)d_ws;
    float* hbufE  = ws;                      // 245760 (zeroed)
    float* ph1    = ws + 245760;             // 2048   (zeroed)
    float* ph2    = ws + 247808;             // 2048   (zeroed)
    int*   flagsE   = (int*)(ws + 249856);   // 7680   (zeroed)
    int*   flagsP1F = (int*)(ws + 257536);   // 2048   (zeroed)
    int*   flagsP1B = (int*)(ws + 259584);   // 2048   (zeroed)
    int*   flagsP2F = (int*)(ws + 261632);   // 2048   (zeroed)
    int*   flagsP2B = (int*)(ws + 263680);   // 2048   (zeroed)
    int*   flagsDA  = (int*)(ws + 265728);   // 64     (zeroed)
    int*   flagsDB  = (int*)(ws + 265792);   // 2048   (zeroed)
    int*   flagsDC  = (int*)(ws + 267840);   // 2048   (zeroed) -> zero end 269888
    float* xp1f  = ws + 269888;              // 245760
    float* xp1b  = ws + 515648;              // 245760
    float* f1    = ws + 761408;              // 61440
    float* b1o   = ws + 822848;              // 61440
    float* x2    = ws + 884288;              // 122880
    float* xp2f  = ws + 1007168;             // 122880
    float* xp2b  = ws + 1130048;             // 122880
    float* f2    = ws + 1252928;             // 30720
    float* b2o   = ws + 1283648;             // 30720
    float* ctxb  = ws + 1314368;             // 61440
    float* hdec  = ws + 1375808;             // 512
    float* inp   = ws + 1376320;             // 16
    float* appl  = ws + 1376336;             // 1024
    float* obuf  = ws + 1377360;             // 512

    init_k<<<256, 256, 0, stream>>>(ws);

    enc_all<<<240, 256, 0, stream>>>(data, enc_Wih, enc_Whh, enc_bih, enc_bhh,
                                     hbufE, flagsE);
    // final h_enc = hbufE buffer 0 (step 64 writes buf (63+1)&1 = 0); view as 120x1024
    gemm_xp<<<128, 256, 0, stream>>>(hbufE, 120, 1024, 0, p1f_Wih, p1f_bih, p1f_bhh, xp1f);
    gemm_xp<<<128, 256, 0, stream>>>(hbufE, 120, 1024, 1, p1b_Wih, p1b_bih, p1b_bhh, xp1b);
    pyr_rec<<<128, 256, 0, stream>>>(xp1f, xp1b, p1f_Whh, p1b_Whh, ph1, f1, b1o, 120,
                                     flagsP1F, flagsP1B);
    x2_assemble<<<60, 256, 0, stream>>>(f1, b1o, x2);
    gemm_xp<<<64, 256, 0, stream>>>(x2, 60, 2048, 0, p2f_Wih, p2f_bih, p2f_bhh, xp2f);
    gemm_xp<<<64, 256, 0, stream>>>(x2, 60, 2048, 1, p2b_Wih, p2b_bih, p2b_bhh, xp2b);
    pyr_rec<<<128, 256, 0, stream>>>(xp2f, xp2b, p2f_Whh, p2b_Whh, ph2, f2, b2o, 60,
                                     flagsP2F, flagsP2B);
    ctx_k<<<60, 256, 0, stream>>>(f2, b2o, ctxb, hdec, inp);
    dec_k<<<66, 256, 0, stream>>>(attn_W, attn_b, comb_W, comb_b,
                                  gru_Wih, gru_Whh, gru_bih, gru_bhh,
                                  out_W, out_b, ctxb, hdec, inp, appl, obuf,
                                  (float*)d_out, flagsDA, flagsDB, flagsDC);
}

// Round 4
// 3059.269 us; speedup vs baseline: 2.3693x; 1.4363x over previous
//
#include <hip/hip_runtime.h>
#include <math.h>

// Model dims: H=512 D=128 L=8 T=64 W=240 CTX=60 NSTEPS=30

typedef __attribute__((ext_vector_type(8))) short short8;
typedef __attribute__((ext_vector_type(4))) float floatx4;

__device__ __forceinline__ float sigf(float x) { return 1.f / (1.f + __expf(-x)); }
__device__ __forceinline__ float tanh_f(float x) {
    float e = __expf(2.f * x);
    return 1.f - 2.f / (e + 1.f);
}
__device__ __forceinline__ unsigned short f2b(float x) {   // fp32 -> bf16 RNE
    unsigned u = __float_as_uint(x);
    unsigned r = (u + 0x7FFFu + ((u >> 16) & 1u)) >> 16;
    return (unsigned short)r;
}

__device__ __forceinline__ float gld(const float* p) {
    return __hip_atomic_load(p, __ATOMIC_RELAXED, __HIP_MEMORY_SCOPE_AGENT);
}
__device__ __forceinline__ void gst(float* p, float v) {
    __hip_atomic_store(p, v, __ATOMIC_RELAXED, __HIP_MEMORY_SCOPE_AGENT);
}
__device__ __forceinline__ unsigned gldu(const unsigned* p) {
    return __hip_atomic_load(p, __ATOMIC_RELAXED, __HIP_MEMORY_SCOPE_AGENT);
}
__device__ __forceinline__ void gstu(unsigned* p, unsigned v) {
    __hip_atomic_store(p, v, __ATOMIC_RELAXED, __HIP_MEMORY_SCOPE_AGENT);
}
__device__ __forceinline__ void set_flag(int* f, int v) {
    __hip_atomic_store(f, v, __ATOMIC_RELEASE, __HIP_MEMORY_SCOPE_AGENT);
}
__device__ __forceinline__ void wait_flag_ge(int* f, int ep) {
    while (__hip_atomic_load(f, __ATOMIC_ACQUIRE, __HIP_MEMORY_SCOPE_AGENT) < ep)
        __builtin_amdgcn_s_sleep(1);
}

// ---------------------------------------------------------------------------
// init: zero [hbufF | ph1 | ph2 | all flag arrays] = 147008 floats
// ---------------------------------------------------------------------------
__global__ void init_k(float* __restrict__ ws) {
    for (int i = blockIdx.x * blockDim.x + threadIdx.x; i < 147008; i += gridDim.x * blockDim.x)
        ws[i] = 0.f;
}

// ---------------------------------------------------------------------------
// Encoder, ONE persistent launch, 64 steps, bf16 MFMA.
// grid 240 = fg(15)*ds(16). Block: 128 gate rows (32 h-dims) x 16 frames.
// Wave w owns dims ds*32+8w..+8 (32 rows over i,f,g,o), full K=640.
// Weights: bf16 B-frags in VGPRs (loaded once). Acts: LDS in A-frag layout.
// h exchanged between blocks as bf16 frag chunks in hbufF[2][15][16][64][4u].
// ---------------------------------------------------------------------------
__global__ void __launch_bounds__(256, 1) enc_all(
    const float* __restrict__ data,
    const float* __restrict__ Wih, const float* __restrict__ Whh,
    const float* __restrict__ bih, const float* __restrict__ bhh,
    unsigned* __restrict__ hbufF,   // [2][15][16][64] x uint4
    float* __restrict__ henc,       // [240][512] fp32 final h
    int* __restrict__ flags)        // [240][32]
{
    __shared__ short act2[20 * 64 * 8];     // A-frags: [kt][lane][8 bf16]
    __shared__ float gw[4][640];            // per-wave gates [rr][f], stride 20
    __shared__ float cs[512];               // c[f*32 + local_dim]
    __shared__ short hw[4][16][8];          // h bf16 staging [w][f][dp]
    __shared__ float biasL[4][4][8];        // [w][g][dp]

    const int tid = threadIdx.x;
    const int fg = blockIdx.x >> 4, ds = blockIdx.x & 15;
    const int w = tid >> 6, lane = tid & 63;
    const int n = lane & 15, q = lane >> 4;

    // ---- load weight B-frags into registers (once) ----
    short8 bfrag[2][20];
#pragma unroll
    for (int nt = 0; nt < 2; ++nt) {
        int rr = nt * 16 + n;
        int g = rr >> 3, dp = rr & 7;
        int grow = g * 512 + ds * 32 + w * 8 + dp;
#pragma unroll
        for (int kt = 0; kt < 20; ++kt) {
            int k0 = kt * 32 + q * 8;
            const float* src = (k0 < 512) ? (Whh + (size_t)grow * 512 + k0)
                                          : (Wih + (size_t)grow * 128 + (k0 - 512));
            float4 lo = *(const float4*)src;
            float4 hi = *(const float4*)(src + 4);
            short8 bf;
            bf[0] = (short)f2b(lo.x); bf[1] = (short)f2b(lo.y);
            bf[2] = (short)f2b(lo.z); bf[3] = (short)f2b(lo.w);
            bf[4] = (short)f2b(hi.x); bf[5] = (short)f2b(hi.y);
            bf[6] = (short)f2b(hi.z); bf[7] = (short)f2b(hi.w);
            bfrag[nt][kt] = bf;
        }
    }
    if (tid < 128) {
        int w2 = tid >> 5, rr = tid & 31;
        int g = rr >> 3, dp = rr & 7;
        int grow = g * 512 + ds * 32 + w2 * 8 + dp;
        biasL[w2][g][dp] = bih[grow] + bhh[grow];
    }
    for (int i = tid; i < 512; i += 256) cs[i] = 0.f;
    __syncthreads();

    unsigned* a2u = (unsigned*)act2;

    for (int t = 0; t < 64; ++t) {
        if (t > 0) {
            if (tid < 16) wait_flag_ge(&flags[(fg * 16 + tid) * 32], t);
        }
        __syncthreads();

        // ---- stage act2: h frag-chunks (kt 0..15) from hbufF ----
        {
            const unsigned* hsrc = hbufF + (size_t)(((t & 1) * 15 + fg) * 16) * 64 * 4;
            for (int i = tid; i < 4096; i += 256) a2u[i] = gldu(hsrc + i);
            // x chunks (kt 16..19) straight from fp32 data (pre-launch data, plain loads)
            int kt2 = tid >> 6, l2 = tid & 63, f2 = l2 & 15, q2 = l2 >> 4;
            const float* xs = data + ((size_t)t * 240 + fg * 16 + f2) * 128 + kt2 * 32 + q2 * 8;
            float4 lo = *(const float4*)xs;
            float4 hi = *(const float4*)(xs + 4);
            short8 xp;
            xp[0] = (short)f2b(lo.x); xp[1] = (short)f2b(lo.y);
            xp[2] = (short)f2b(lo.z); xp[3] = (short)f2b(lo.w);
            xp[4] = (short)f2b(hi.x); xp[5] = (short)f2b(hi.y);
            xp[6] = (short)f2b(hi.z); xp[7] = (short)f2b(hi.w);
            *(short8*)&act2[((16 + kt2) * 64 + l2) * 8] = xp;
        }
        __syncthreads();

        // ---- MFMA: gates for 32 rows x 16 frames, K=640 ----
        floatx4 acc0 = {0.f, 0.f, 0.f, 0.f};
        floatx4 acc1 = {0.f, 0.f, 0.f, 0.f};
#pragma unroll
        for (int kt = 0; kt < 20; ++kt) {
            short8 a = *(short8*)&act2[(kt * 64 + lane) * 8];
            acc0 = __builtin_amdgcn_mfma_f32_16x16x32_bf16(a, bfrag[0][kt], acc0, 0, 0, 0);
            acc1 = __builtin_amdgcn_mfma_f32_16x16x32_bf16(a, bfrag[1][kt], acc1, 0, 0, 0);
        }
        // D[m=4q+reg][n] -> gw[rr][m] (m contiguous)
        *(floatx4*)&gw[w][(0 * 16 + n) * 20 + 4 * q] = acc0;
        *(floatx4*)&gw[w][(1 * 16 + n) * 20 + 4 * q] = acc1;
        // (DS ops are in-order per wave: no barrier needed before wave-local reads)

        // ---- wave-local pointwise: 16 frames x 8 dims ----
        int nb = (t + 1) & 1;
#pragma unroll
        for (int it = 0; it < 2; ++it) {
            int f = lane & 15, dp = q + 4 * it;
            float gi = gw[w][(0 * 8 + dp) * 20 + f] + biasL[w][0][dp];
            float gf = gw[w][(1 * 8 + dp) * 20 + f] + biasL[w][1][dp];
            float gg = gw[w][(2 * 8 + dp) * 20 + f] + biasL[w][2][dp];
            float go = gw[w][(3 * 8 + dp) * 20 + f] + biasL[w][3][dp];
            int ci = f * 32 + w * 8 + dp;
            float cc = cs[ci];
            float cn = sigf(gf) * cc + sigf(gi) * tanh_f(gg);
            float hn = sigf(go) * tanh_f(cn);
            cs[ci] = cn;
            hw[w][f][dp] = (short)f2b(hn);
            if (t == 63)
                gst(&henc[(size_t)(fg * 16 + f) * 512 + ds * 32 + w * 8 + dp], hn);
        }
        // ---- pack h chunk (this wave's dim-octet = kt ds, q-slot w) ----
        if (lane < 16) {
            const unsigned* hwp = (const unsigned*)&hw[w][lane][0];
            unsigned* dst = hbufF + (size_t)((((nb * 15 + fg) * 16 + ds) * 64) + w * 16 + lane) * 4;
            gstu(dst + 0, hwp[0]); gstu(dst + 1, hwp[1]);
            gstu(dst + 2, hwp[2]); gstu(dst + 3, hwp[3]);
        }
        __syncthreads();
        if (tid == 0) set_flag(&flags[(fg * 16 + ds) * 32], t + 1);
    }
}

// ---------------------------------------------------------------------------
// xp GEMM: C[M][2048] = A[M][K] @ Wv[2048][K]^T + ba + bb (rev flips A rows)
// ---------------------------------------------------------------------------
__global__ void __launch_bounds__(256) gemm_xp(
    const float* __restrict__ A, int M, int K, int rev,
    const float* __restrict__ Wv, const float* __restrict__ ba, const float* __restrict__ bb,
    float* __restrict__ C)
{
    __shared__ float At[16][66];
    __shared__ float Wt[128][66];
    const int tid = threadIdx.x;
    const int nt = blockIdx.x & 15, mt = blockIdx.x >> 4;
    const int rp = tid >> 2, fq = tid & 3;
    const int lr0 = 2 * rp, lr1 = lr0 + 1;
    const int n0 = nt * 128 + lr0, n1 = n0 + 1;

    float acc0[4], acc1[4];
    {
        float b0 = ba[n0] + bb[n0], b1 = ba[n1] + bb[n1];
#pragma unroll
        for (int j = 0; j < 4; ++j) { acc0[j] = b0; acc1[j] = b1; }
    }

    for (int kt = 0; kt < K; kt += 64) {
        {
            int f = tid >> 4, c4 = tid & 15;
            int m = mt * 16 + f;
            float4 v = make_float4(0.f, 0.f, 0.f, 0.f);
            if (m < M) {
                int ar = rev ? (M - 1 - m) : m;
                v = ((const float4*)(A + (size_t)ar * K + kt))[c4];
            }
            At[f][c4 * 4 + 0] = v.x; At[f][c4 * 4 + 1] = v.y;
            At[f][c4 * 4 + 2] = v.z; At[f][c4 * 4 + 3] = v.w;
        }
        for (int i = tid; i < 2048; i += 256) {
            int lr = i >> 4, c4 = i & 15;
            float4 v = ((const float4*)(Wv + (size_t)(nt * 128 + lr) * K + kt))[c4];
            Wt[lr][c4 * 4 + 0] = v.x; Wt[lr][c4 * 4 + 1] = v.y;
            Wt[lr][c4 * 4 + 2] = v.z; Wt[lr][c4 * 4 + 3] = v.w;
        }
        __syncthreads();
        const float2* w0p = (const float2*)(&Wt[lr0][0]);
        const float2* w1p = (const float2*)(&Wt[lr1][0]);
#pragma unroll 8
        for (int kh = 0; kh < 32; ++kh) {
            float2 w0 = w0p[kh], w1 = w1p[kh];
#pragma unroll
            for (int j = 0; j < 4; ++j) {
                float2 av = ((const float2*)(&At[4 * fq + j][0]))[kh];
                acc0[j] += w0.x * av.x + w0.y * av.y;
                acc1[j] += w1.x * av.x + w1.y * av.y;
            }
        }
        __syncthreads();
    }
#pragma unroll
    for (int j = 0; j < 4; ++j) {
        int m = mt * 16 + 4 * fq + j;
        if (m < M) {
            C[(size_t)m * 2048 + n0] = acc0[j];
            C[(size_t)m * 2048 + n1] = acc1[j];
        }
    }
}

// ---------------------------------------------------------------------------
// Pyramidal bi-LSTM recurrence. grid 128 = dir(2) x blk(64); 8 dims/block.
// ---------------------------------------------------------------------------
__global__ void __launch_bounds__(256) pyr_rec(
    const float* __restrict__ xpF, const float* __restrict__ xpB,
    const float* __restrict__ WhhF, const float* __restrict__ WhhB,
    float* __restrict__ hbuf,  // [buf2][dir2][512]
    float* __restrict__ outF, float* __restrict__ outB,
    int steps, int* __restrict__ flagF, int* __restrict__ flagB)
{
    const int tid = threadIdx.x;
    const int dir = blockIdx.x >> 6, blk = blockIdx.x & 63;
    const float* xp  = dir ? xpB : xpF;
    const float* Whh = dir ? WhhB : WhhF;
    float* outp = dir ? outB : outF;
    int* flag = dir ? flagB : flagF;

    __shared__ float Wl[32][516];
    __shared__ float hcur[512];
    __shared__ float red[32][9];
    __shared__ float gv[32];

    for (int i = tid; i < 4096; i += 256) {
        int lr = i >> 7, c4 = i & 127;
        int grow = (lr >> 3) * 512 + blk * 8 + (lr & 7);
        float4 v = ((const float4*)(Whh + (size_t)grow * 512))[c4];
        *(float4*)&Wl[lr][c4 * 4] = v;
    }
    float creg = 0.f;
    const int lr = tid & 31, seg = tid >> 5;
    __syncthreads();

    for (int t = 0; t < steps; ++t) {
        if (t > 0) {
            if (tid < 64) wait_flag_ge(&flag[tid * 32], t);
        }
        __syncthreads();
        int hb = t & 1;
        for (int i = tid; i < 512; i += 256)
            hcur[i] = gld(&hbuf[(hb * 2 + dir) * 512 + i]);
        __syncthreads();

        const float* wr = &Wl[lr][seg * 64];
        const float* hr = &hcur[seg * 64];
        float a = 0.f;
#pragma unroll
        for (int k4 = 0; k4 < 16; ++k4) {
            float4 w = *(const float4*)(wr + 4 * k4);
            float4 h4 = *(const float4*)(hr + 4 * k4);
            a += w.x*h4.x + w.y*h4.y + w.z*h4.z + w.w*h4.w;
        }
        red[lr][seg] = a;
        __syncthreads();

        if (tid < 32) {
            int grow = (tid >> 3) * 512 + blk * 8 + (tid & 7);
            float g = xp[(size_t)t * 2048 + grow];
#pragma unroll
            for (int s2 = 0; s2 < 8; ++s2) g += red[tid][s2];
            gv[tid] = g;
        }
        __syncthreads();
        if (tid < 8) {
            float i_ = sigf(gv[tid]), f_ = sigf(gv[8 + tid]);
            float g_ = tanh_f(gv[16 + tid]), o_ = sigf(gv[24 + tid]);
            creg = f_ * creg + i_ * g_;
            float hn = o_ * tanh_f(creg);
            int d = blk * 8 + tid;
            gst(&hbuf[((1 - hb) * 2 + dir) * 512 + d], hn);
            int row = dir ? (steps - 1 - t) : t;
            outp[(size_t)row * 512 + d] = hn;
        }
        __syncthreads();
        if (tid == 0) set_flag(&flag[blk * 32], t + 1);
    }
}

__global__ void x2_assemble(const float* __restrict__ f1, const float* __restrict__ b1o,
                            float* __restrict__ x2)
{
    int j = blockIdx.x;
    for (int k = threadIdx.x; k < 2048; k += 256) {
        int q = k >> 9, r = k & 511;
        const float* src = (q & 1) ? b1o : f1;
        int row = 2 * j + (q >> 1);
        x2[(size_t)j * 2048 + k] = src[(size_t)row * 512 + r];
    }
}

__global__ void ctx_k(const float* __restrict__ f2, const float* __restrict__ b2o,
                      float* __restrict__ ctx, float* __restrict__ hdec, float* __restrict__ inp)
{
    int j = blockIdx.x;
    for (int k = threadIdx.x; k < 1024; k += 256)
        ctx[(size_t)j * 1024 + k] = (k < 512) ? f2[(size_t)j * 512 + k]
                                              : b2o[(size_t)j * 512 + k - 512];
    if (j == 0) {
        for (int i = threadIdx.x; i < 512; i += 256) hdec[i] = f2[59 * 512 + i];
        if (threadIdx.x < 8) inp[threadIdx.x] = (threadIdx.x == 7) ? 1.f : 0.f;
    }
}

// ---------------------------------------------------------------------------
// Decoder: 66 blocks, dependency-shaped epoch flags (see R2/R3 notes).
// ---------------------------------------------------------------------------
__global__ void __launch_bounds__(256) dec_k(
    const float* __restrict__ attn_W, const float* __restrict__ attn_b,
    const float* __restrict__ comb_W, const float* __restrict__ comb_b,
    const float* __restrict__ gWih, const float* __restrict__ gWhh,
    const float* __restrict__ gbih, const float* __restrict__ gbhh,
    const float* __restrict__ outW, const float* __restrict__ outb,
    const float* __restrict__ ctx,
    float* __restrict__ hdec, float* __restrict__ inp,
    float* __restrict__ applied, float* __restrict__ obuf,
    float* __restrict__ dout,
    int* __restrict__ flagA, int* __restrict__ flagB, int* __restrict__ flagC)
{
    const int tid = threadIdx.x, bid = blockIdx.x;
    __shared__ float pool[33056];
    __shared__ float hl[512];
    __shared__ float xl[1036];
    __shared__ float inpl[8];
    __shared__ float red4[60][5];
    __shared__ float red8[24][9];
    __shared__ float red32[8][33];
    __shared__ float ghl[24], gil[24];
    __shared__ float zz[60], aw[60], zd[8];
    __shared__ float ms[1];

    const bool attn_role = (bid < 2);
    float* ctxL = pool;                       // [60][516]
    float* Wg = pool;                         // [24][516]
    float* Wi = pool + 24 * 516;              // [24][516]
    float* Wc = pool + 48 * 516;              // [8][1036]
    const int gbid = bid - 2;
    const int dbase = gbid * 8;

    if (attn_role) {
        for (int i = tid; i < 7680; i += 256) {
            int j = i >> 7, c4 = i & 127;
            float4 v = ((const float4*)(ctx + (size_t)j * 1024 + bid * 512))[c4];
            *(float4*)&ctxL[j * 516 + c4 * 4] = v;
        }
    } else {
        for (int i = tid; i < 3072; i += 256) {
            int r = i >> 7, c4 = i & 127;
            int grow = (r >> 3) * 512 + dbase + (r & 7);
            *(float4*)&Wg[r * 516 + c4 * 4] = ((const float4*)(gWhh + (size_t)grow * 512))[c4];
            *(float4*)&Wi[r * 516 + c4 * 4] = ((const float4*)(gWih + (size_t)grow * 512))[c4];
        }
        for (int i = tid; i < 2064; i += 256) {
            int r = i / 258, c4 = i % 258;
            *(float4*)&Wc[r * 1036 + c4 * 4] =
                ((const float4*)(comb_W + (size_t)(dbase + r) * 1032))[c4];
        }
    }
    __syncthreads();

    for (int s = 0; s < 30; ++s) {
        if (s > 0) {
            if (tid < 64) wait_flag_ge(&flagC[tid * 32], s);
        }
        __syncthreads();
        for (int i = tid; i < 512; i += 256) hl[i] = gld(&hdec[i]);
        __syncthreads();

        if (attn_role) {
            if (s > 0) {
                {
                    int row = tid >> 5, sg = tid & 31;
                    const float* wr = outW + (size_t)row * 512 + sg * 16;
                    const float* hp = hl + sg * 16;
                    float a = 0.f;
#pragma unroll
                    for (int k = 0; k < 16; ++k) a += wr[k] * hp[k];
                    red32[row][sg] = a;
                }
                __syncthreads();
                if (tid < 8) {
                    float a = outb[tid];
#pragma unroll
                    for (int g2 = 0; g2 < 32; ++g2) a += red32[tid][g2];
                    zd[tid] = a;
                }
                __syncthreads();
                if (tid == 0) {
                    float m = zd[0];
                    for (int l = 1; l < 8; ++l) m = fmaxf(m, zd[l]);
                    float ss = 0.f;
                    for (int l = 0; l < 8; ++l) ss += __expf(zd[l] - m);
                    ms[0] = m + __logf(ss);
                }
                __syncthreads();
                if (tid < 8) {
                    float lp = zd[tid] - ms[0];
                    inpl[tid] = lp;
                    if (bid == 0) { dout[(s - 1) * 8 + tid] = lp; gst(&inp[tid], lp); }
                }
            } else {
                if (tid < 8) inpl[tid] = gld(&inp[tid]);
            }
            __syncthreads();
            {
                int r = tid >> 2, sg = tid & 3;
                if (r < 60) {
                    int k0 = sg * 130;
                    const float* wr = attn_W + (size_t)r * 520 + k0;
                    float a = 0.f;
                    for (int k = 0; k < 130; ++k) {
                        int kk = k0 + k;
                        float x = (kk < 8) ? inpl[kk] : hl[kk - 8];
                        a += wr[k] * x;
                    }
                    red4[r][sg] = a;
                }
            }
            __syncthreads();
            if (tid < 60)
                zz[tid] = attn_b[tid] + red4[tid][0] + red4[tid][1] + red4[tid][2] + red4[tid][3];
            __syncthreads();
            if (tid == 0) {
                float m = zz[0];
                for (int j = 1; j < 60; ++j) m = fmaxf(m, zz[j]);
                float ss = 0.f;
                for (int j = 0; j < 60; ++j) { float e = __expf(zz[j] - m); aw[j] = e; ss += e; }
                float inv = 1.f / ss;
                for (int j = 0; j < 60; ++j) aw[j] *= inv;
            }
            __syncthreads();
            for (int cc = tid; cc < 512; cc += 256) {
                float a = 0.f;
                for (int j = 0; j < 60; ++j) a += aw[j] * ctxL[j * 516 + cc];
                gst(&applied[bid * 512 + cc], a);
            }
            __syncthreads();
            if (tid == 0) set_flag(&flagA[bid * 32], s + 1);
        } else {
            {
                if (tid < 192) {
                    int r = tid >> 3, sg = tid & 7;
                    const float* wr = Wg + r * 516 + sg * 64;
                    const float* hp = hl + sg * 64;
                    float a = 0.f;
#pragma unroll
                    for (int k4 = 0; k4 < 16; ++k4) {
                        float4 w = *(const float4*)(wr + 4 * k4);
                        float4 h4 = *(const float4*)(hp + 4 * k4);
                        a += w.x*h4.x + w.y*h4.y + w.z*h4.z + w.w*h4.w;
                    }
                    red8[r][sg] = a;
                }
            }
            __syncthreads();
            if (tid < 24) {
                int grow = (tid >> 3) * 512 + dbase + (tid & 7);
                float a = gbhh[grow];
#pragma unroll
                for (int g2 = 0; g2 < 8; ++g2) a += red8[tid][g2];
                ghl[tid] = a;
            }
            if (tid < 2) wait_flag_ge(&flagA[tid * 32], s + 1);
            __syncthreads();
            if (tid < 8) xl[tid] = gld(&inp[tid]);
            for (int i = tid; i < 1024; i += 256) xl[8 + i] = gld(&applied[i]);
            __syncthreads();
            {
                int row = tid >> 5, sg = tid & 31;
                const float* wr = Wc + row * 1036;
                float a = 0.f;
                for (int k = sg; k < 1032; k += 32) a += wr[k] * xl[k];
                red32[row][sg] = a;
            }
            __syncthreads();
            if (tid < 8) {
                float a = comb_b[dbase + tid];
#pragma unroll
                for (int g2 = 0; g2 < 32; ++g2) a += red32[tid][g2];
                gst(&obuf[dbase + tid], fmaxf(a, 0.f));
            }
            __syncthreads();
            if (tid == 0) set_flag(&flagB[gbid * 32], s + 1);
            if (tid < 64) wait_flag_ge(&flagB[tid * 32], s + 1);
            __syncthreads();
            for (int i = tid; i < 512; i += 256) xl[i] = gld(&obuf[i]);
            __syncthreads();
            {
                if (tid < 192) {
                    int r = tid >> 3, sg = tid & 7;
                    const float* wr = Wi + r * 516 + sg * 64;
                    const float* op = xl + sg * 64;
                    float a = 0.f;
#pragma unroll
                    for (int k4 = 0; k4 < 16; ++k4) {
                        float4 w = *(const float4*)(wr + 4 * k4);
                        float4 o4 = *(const float4*)(op + 4 * k4);
                        a += w.x*o4.x + w.y*o4.y + w.z*o4.z + w.w*o4.w;
                    }
                    red8[r][sg] = a;
                }
            }
            __syncthreads();
            if (tid < 24) {
                int grow = (tid >> 3) * 512 + dbase + (tid & 7);
                float a = gbih[grow];
#pragma unroll
                for (int g2 = 0; g2 < 8; ++g2) a += red8[tid][g2];
                gil[tid] = a;
            }
            __syncthreads();
            if (tid < 8) {
                float r_ = sigf(gil[tid] + ghl[tid]);
                float z_ = sigf(gil[8 + tid] + ghl[8 + tid]);
                float n_ = tanh_f(gil[16 + tid] + r_ * ghl[16 + tid]);
                float hnew = (1.f - z_) * n_ + z_ * hl[dbase + tid];
                gst(&hdec[dbase + tid], hnew);
            }
            __syncthreads();
            if (tid == 0) set_flag(&flagC[gbid * 32], s + 1);
        }
    }

    if (bid == 0) {
        if (tid < 64) wait_flag_ge(&flagC[tid * 32], 30);
        __syncthreads();
        for (int i = tid; i < 512; i += 256) hl[i] = gld(&hdec[i]);
        __syncthreads();
        {
            int row = tid >> 5, sg = tid & 31;
            const float* wr = outW + (size_t)row * 512 + sg * 16;
            const float* hp = hl + sg * 16;
            float a = 0.f;
#pragma unroll
            for (int k = 0; k < 16; ++k) a += wr[k] * hp[k];
            red32[row][sg] = a;
        }
        __syncthreads();
        if (tid < 8) {
            float a = outb[tid];
#pragma unroll
            for (int g2 = 0; g2 < 32; ++g2) a += red32[tid][g2];
            zd[tid] = a;
        }
        __syncthreads();
        if (tid == 0) {
            float m = zd[0];
            for (int l = 1; l < 8; ++l) m = fmaxf(m, zd[l]);
            float ss = 0.f;
            for (int l = 0; l < 8; ++l) ss += __expf(zd[l] - m);
            ms[0] = m + __logf(ss);
        }
        __syncthreads();
        if (tid < 8) dout[29 * 8 + tid] = zd[tid] - ms[0];
    }
}

// ---------------------------------------------------------------------------
extern "C" void kernel_launch(void* const* d_in, const int* in_sizes, int n_in,
                              void* d_out, int out_size, void* d_ws, size_t ws_size,
                              hipStream_t stream) {
    (void)in_sizes; (void)n_in; (void)out_size; (void)ws_size;
    const float* data    = (const float*)d_in[0];
    const float* enc_Wih = (const float*)d_in[1];
    const float* enc_Whh = (const float*)d_in[2];
    const float* enc_bih = (const float*)d_in[3];
    const float* enc_bhh = (const float*)d_in[4];
    const float* p1f_Wih = (const float*)d_in[5];
    const float* p1f_Whh = (const float*)d_in[6];
    const float* p1f_bih = (const float*)d_in[7];
    const float* p1f_bhh = (const float*)d_in[8];
    const float* p1b_Wih = (const float*)d_in[9];
    const float* p1b_Whh = (const float*)d_in[10];
    const float* p1b_bih = (const float*)d_in[11];
    const float* p1b_bhh = (const float*)d_in[12];
    const float* p2f_Wih = (const float*)d_in[13];
    const float* p2f_Whh = (const float*)d_in[14];
    const float* p2f_bih = (const float*)d_in[15];
    const float* p2f_bhh = (const float*)d_in[16];
    const float* p2b_Wih = (const float*)d_in[17];
    const float* p2b_Whh = (const float*)d_in[18];
    const float* p2b_bih = (const float*)d_in[19];
    const float* p2b_bhh = (const float*)d_in[20];
    const float* attn_W  = (const float*)d_in[21];
    const float* attn_b  = (const float*)d_in[22];
    const float* comb_W  = (const float*)d_in[23];
    const float* comb_b  = (const float*)d_in[24];
    const float* gru_Wih = (const float*)d_in[25];
    const float* gru_Whh = (const float*)d_in[26];
    const float* gru_bih = (const float*)d_in[27];
    const float* gru_bhh = (const float*)d_in[28];
    const float* out_W   = (const float*)d_in[29];
    const float* out_b   = (const float*)d_in[30];

    float* ws = (float*)d_ws;
    // zeroed region [0 .. 147008)
    unsigned* hbufF = (unsigned*)ws;         // 122880 words (2x15x16x64 uint4)
    float* ph1      = ws + 122880;           // 2048
    float* ph2      = ws + 124928;           // 2048
    int* flagsE     = (int*)(ws + 126976);   // 7680
    int* flagsP1F   = (int*)(ws + 134656);   // 2048
    int* flagsP1B   = (int*)(ws + 136704);   // 2048
    int* flagsP2F   = (int*)(ws + 138752);   // 2048
    int* flagsP2B   = (int*)(ws + 140800);   // 2048
    int* flagsDA    = (int*)(ws + 142848);   // 64
    int* flagsDB    = (int*)(ws + 142912);   // 2048
    int* flagsDC    = (int*)(ws + 144960);   // 2048  -> zero end = 147008
    // non-zeroed scratch
    float* henc  = ws + 147008;              // 122880
    float* xp1f  = ws + 269888;              // 245760
    float* xp1b  = ws + 515648;              // 245760
    float* f1    = ws + 761408;              // 61440
    float* b1o   = ws + 822848;              // 61440
    float* x2    = ws + 884288;              // 122880
    float* xp2f  = ws + 1007168;             // 122880
    float* xp2b  = ws + 1130048;             // 122880
    float* f2    = ws + 1252928;             // 30720
    float* b2o   = ws + 1283648;             // 30720
    float* ctxb  = ws + 1314368;             // 61440
    float* hdec  = ws + 1375808;             // 512
    float* inp   = ws + 1376320;             // 16
    float* appl  = ws + 1376336;             // 1024
    float* obuf  = ws + 1377360;             // 512

    init_k<<<256, 256, 0, stream>>>(ws);

    enc_all<<<240, 256, 0, stream>>>(data, enc_Wih, enc_Whh, enc_bih, enc_bhh,
                                     hbufF, henc, flagsE);
    // henc = final h (240x512) fp32; x1 = henc.reshape(120,1024)
    gemm_xp<<<128, 256, 0, stream>>>(henc, 120, 1024, 0, p1f_Wih, p1f_bih, p1f_bhh, xp1f);
    gemm_xp<<<128, 256, 0, stream>>>(henc, 120, 1024, 1, p1b_Wih, p1b_bih, p1b_bhh, xp1b);
    pyr_rec<<<128, 256, 0, stream>>>(xp1f, xp1b, p1f_Whh, p1b_Whh, ph1, f1, b1o, 120,
                                     flagsP1F, flagsP1B);
    x2_assemble<<<60, 256, 0, stream>>>(f1, b1o, x2);
    gemm_xp<<<64, 256, 0, stream>>>(x2, 60, 2048, 0, p2f_Wih, p2f_bih, p2f_bhh, xp2f);
    gemm_xp<<<64, 256, 0, stream>>>(x2, 60, 2048, 1, p2b_Wih, p2b_bih, p2b_bhh, xp2b);
    pyr_rec<<<128, 256, 0, stream>>>(xp2f, xp2b, p2f_Whh, p2b_Whh, ph2, f2, b2o, 60,
                                     flagsP2F, flagsP2B);
    ctx_k<<<60, 256, 0, stream>>>(f2, b2o, ctxb, hdec, inp);
    dec_k<<<66, 256, 0, stream>>>(attn_W, attn_b, comb_W, comb_b,
                                  gru_Wih, gru_Whh, gru_bih, gru_bhh,
                                  out_W, out_b, ctxb, hdec, inp, appl, obuf,
                                  (float*)d_out, flagsDA, flagsDB, flagsDC);
}

// Round 5
// 2032.277 us; speedup vs baseline: 3.5666x; 1.5053x over previous
//
#include <hip/hip_runtime.h>
#include <math.h>

// Model dims: H=512 D=128 L=8 T=64 W=240 CTX=60 NSTEPS=30

typedef __attribute__((ext_vector_type(8))) short short8;
typedef __attribute__((ext_vector_type(4))) float floatx4;

__device__ __forceinline__ float sigf(float x) { return 1.f / (1.f + __expf(-x)); }
__device__ __forceinline__ float tanh_f(float x) {
    float e = __expf(2.f * x);
    return 1.f - 2.f / (e + 1.f);
}
__device__ __forceinline__ unsigned short f2b(float x) {   // fp32 -> bf16 RNE
    unsigned u = __float_as_uint(x);
    unsigned r = (u + 0x7FFFu + ((u >> 16) & 1u)) >> 16;
    return (unsigned short)r;
}

// All cross-block data/flags use RELAXED agent-scope atomics (sc1: bypass
// L1/L2, coherent at MALL). NO acquire/release in hot loops: on gfx950 an
// acquire load emits buffer_inv and a release store emits buffer_wbl2 —
// executed inside spin loops these trash the XCD L2 continuously (R4's
// hidden ~8us/hop). Ordering for flag publication is guaranteed because
// every set_flag is preceded by __syncthreads(), which drains vmcnt(0) for
// all waves => data stores are complete at the coherence point first.
__device__ __forceinline__ float gld(const float* p) {
    return __hip_atomic_load(p, __ATOMIC_RELAXED, __HIP_MEMORY_SCOPE_AGENT);
}
__device__ __forceinline__ void gst(float* p, float v) {
    __hip_atomic_store(p, v, __ATOMIC_RELAXED, __HIP_MEMORY_SCOPE_AGENT);
}
__device__ __forceinline__ unsigned long long gldll(const unsigned long long* p) {
    return __hip_atomic_load(p, __ATOMIC_RELAXED, __HIP_MEMORY_SCOPE_AGENT);
}
__device__ __forceinline__ void gstll(unsigned long long* p, unsigned long long v) {
    __hip_atomic_store(p, v, __ATOMIC_RELAXED, __HIP_MEMORY_SCOPE_AGENT);
}
__device__ __forceinline__ void set_flag(int* f, int v) {
    __hip_atomic_store(f, v, __ATOMIC_RELAXED, __HIP_MEMORY_SCOPE_AGENT);
}
__device__ __forceinline__ void wait_flag_ge(int* f, int ep) {
    while (__hip_atomic_load(f, __ATOMIC_RELAXED, __HIP_MEMORY_SCOPE_AGENT) < ep)
        __builtin_amdgcn_s_sleep(1);
}

// ---------------------------------------------------------------------------
// init: zero [hbufF | ph1 | ph2 | all flag arrays] = 147008 floats
// ---------------------------------------------------------------------------
__global__ void init_k(float* __restrict__ ws) {
    for (int i = blockIdx.x * blockDim.x + threadIdx.x; i < 147008; i += gridDim.x * blockDim.x)
        ws[i] = 0.f;
}

// ---------------------------------------------------------------------------
// Encoder, ONE persistent launch, 64 steps, bf16 MFMA.
// grid 240 = fg(15)*ds(16). Block: 128 gate rows (32 h-dims) x 16 frames.
// Weights: bf16 B-frags in VGPRs (loaded once). Acts: LDS in A-frag layout.
// h exchanged between blocks as bf16 frag chunks (8-byte atomic words).
// ---------------------------------------------------------------------------
__global__ void __launch_bounds__(256, 1) enc_all(
    const float* __restrict__ data,
    const float* __restrict__ Wih, const float* __restrict__ Whh,
    const float* __restrict__ bih, const float* __restrict__ bhh,
    unsigned long long* __restrict__ hbufF,   // [2][15][16][64] x (2 ull)
    float* __restrict__ henc,       // [240][512] fp32 final h
    int* __restrict__ flags)        // [240][32]
{
    __shared__ short act2[20 * 64 * 8];     // A-frags: [kt][lane][8 bf16]
    __shared__ float gw[4][640];            // per-wave gates [rr][f], stride 20
    __shared__ float cs[512];               // c[f*32 + local_dim]
    __shared__ short hw[4][16][8];          // h bf16 staging [w][f][dp]
    __shared__ float biasL[4][4][8];        // [w][g][dp]

    const int tid = threadIdx.x;
    const int fg = blockIdx.x >> 4, ds = blockIdx.x & 15;
    const int w = tid >> 6, lane = tid & 63;
    const int n = lane & 15, q = lane >> 4;

    // ---- load weight B-frags into registers (once) ----
    short8 bfrag[2][20];
#pragma unroll
    for (int nt = 0; nt < 2; ++nt) {
        int rr = nt * 16 + n;
        int g = rr >> 3, dp = rr & 7;
        int grow = g * 512 + ds * 32 + w * 8 + dp;
#pragma unroll
        for (int kt = 0; kt < 20; ++kt) {
            int k0 = kt * 32 + q * 8;
            const float* src = (k0 < 512) ? (Whh + (size_t)grow * 512 + k0)
                                          : (Wih + (size_t)grow * 128 + (k0 - 512));
            float4 lo = *(const float4*)src;
            float4 hi = *(const float4*)(src + 4);
            short8 bf;
            bf[0] = (short)f2b(lo.x); bf[1] = (short)f2b(lo.y);
            bf[2] = (short)f2b(lo.z); bf[3] = (short)f2b(lo.w);
            bf[4] = (short)f2b(hi.x); bf[5] = (short)f2b(hi.y);
            bf[6] = (short)f2b(hi.z); bf[7] = (short)f2b(hi.w);
            bfrag[nt][kt] = bf;
        }
    }
    if (tid < 128) {
        int w2 = tid >> 5, rr = tid & 31;
        int g = rr >> 3, dp = rr & 7;
        int grow = g * 512 + ds * 32 + w2 * 8 + dp;
        biasL[w2][g][dp] = bih[grow] + bhh[grow];
    }
    for (int i = tid; i < 512; i += 256) cs[i] = 0.f;
    __syncthreads();

    unsigned long long* a2ll = (unsigned long long*)act2;

    for (int t = 0; t < 64; ++t) {
        if (t > 0) {
            if (tid < 16) wait_flag_ge(&flags[(fg * 16 + tid) * 32], t);
        }
        __syncthreads();

        // ---- stage act2: h frag-chunks (kt 0..15) from hbufF (8B words) ----
        {
            const unsigned long long* hsrc =
                hbufF + (size_t)(((t & 1) * 15 + fg) * 16) * 64 * 2;
            for (int i = tid; i < 2048; i += 256) a2ll[i] = gldll(hsrc + i);
            // x chunks (kt 16..19) straight from fp32 data (plain loads)
            int kt2 = tid >> 6, l2 = tid & 63, f2 = l2 & 15, q2 = l2 >> 4;
            const float* xs = data + ((size_t)t * 240 + fg * 16 + f2) * 128 + kt2 * 32 + q2 * 8;
            float4 lo = *(const float4*)xs;
            float4 hi = *(const float4*)(xs + 4);
            short8 xp;
            xp[0] = (short)f2b(lo.x); xp[1] = (short)f2b(lo.y);
            xp[2] = (short)f2b(lo.z); xp[3] = (short)f2b(lo.w);
            xp[4] = (short)f2b(hi.x); xp[5] = (short)f2b(hi.y);
            xp[6] = (short)f2b(hi.z); xp[7] = (short)f2b(hi.w);
            *(short8*)&act2[((16 + kt2) * 64 + l2) * 8] = xp;
        }
        __syncthreads();

        // ---- MFMA: gates for 32 rows x 16 frames, K=640 ----
        floatx4 acc0 = {0.f, 0.f, 0.f, 0.f};
        floatx4 acc1 = {0.f, 0.f, 0.f, 0.f};
#pragma unroll
        for (int kt = 0; kt < 20; ++kt) {
            short8 a = *(short8*)&act2[(kt * 64 + lane) * 8];
            acc0 = __builtin_amdgcn_mfma_f32_16x16x32_bf16(a, bfrag[0][kt], acc0, 0, 0, 0);
            acc1 = __builtin_amdgcn_mfma_f32_16x16x32_bf16(a, bfrag[1][kt], acc1, 0, 0, 0);
        }
        *(floatx4*)&gw[w][(0 * 16 + n) * 20 + 4 * q] = acc0;
        *(floatx4*)&gw[w][(1 * 16 + n) * 20 + 4 * q] = acc1;

        // ---- wave-local pointwise: 16 frames x 8 dims ----
        int nb = (t + 1) & 1;
#pragma unroll
        for (int it = 0; it < 2; ++it) {
            int f = lane & 15, dp = q + 4 * it;
            float gi = gw[w][(0 * 8 + dp) * 20 + f] + biasL[w][0][dp];
            float gf = gw[w][(1 * 8 + dp) * 20 + f] + biasL[w][1][dp];
            float gg = gw[w][(2 * 8 + dp) * 20 + f] + biasL[w][2][dp];
            float go = gw[w][(3 * 8 + dp) * 20 + f] + biasL[w][3][dp];
            int ci = f * 32 + w * 8 + dp;
            float cc = cs[ci];
            float cn = sigf(gf) * cc + sigf(gi) * tanh_f(gg);
            float hn = sigf(go) * tanh_f(cn);
            cs[ci] = cn;
            hw[w][f][dp] = (short)f2b(hn);
            if (t == 63)
                gst(&henc[(size_t)(fg * 16 + f) * 512 + ds * 32 + w * 8 + dp], hn);
        }
        // ---- pack h chunk (8B words) ----
        if (lane < 16) {
            const unsigned long long* hwp = (const unsigned long long*)&hw[w][lane][0];
            unsigned long long* dst =
                hbufF + (size_t)((((nb * 15 + fg) * 16 + ds) * 64) + w * 16 + lane) * 2;
            gstll(dst + 0, hwp[0]); gstll(dst + 1, hwp[1]);
        }
        __syncthreads();   // drains vmcnt(0) for all waves before flag set
        if (tid == 0) set_flag(&flags[(fg * 16 + ds) * 32], t + 1);
    }
}

// ---------------------------------------------------------------------------
// xp GEMM: C[M][2048] = A[M][K] @ Wv[2048][K]^T + ba + bb (rev flips A rows)
// ---------------------------------------------------------------------------
__global__ void __launch_bounds__(256) gemm_xp(
    const float* __restrict__ A, int M, int K, int rev,
    const float* __restrict__ Wv, const float* __restrict__ ba, const float* __restrict__ bb,
    float* __restrict__ C)
{
    __shared__ float At[16][66];
    __shared__ float Wt[128][66];
    const int tid = threadIdx.x;
    const int nt = blockIdx.x & 15, mt = blockIdx.x >> 4;
    const int rp = tid >> 2, fq = tid & 3;
    const int lr0 = 2 * rp, lr1 = lr0 + 1;
    const int n0 = nt * 128 + lr0, n1 = n0 + 1;

    float acc0[4], acc1[4];
    {
        float b0 = ba[n0] + bb[n0], b1 = ba[n1] + bb[n1];
#pragma unroll
        for (int j = 0; j < 4; ++j) { acc0[j] = b0; acc1[j] = b1; }
    }

    for (int kt = 0; kt < K; kt += 64) {
        {
            int f = tid >> 4, c4 = tid & 15;
            int m = mt * 16 + f;
            float4 v = make_float4(0.f, 0.f, 0.f, 0.f);
            if (m < M) {
                int ar = rev ? (M - 1 - m) : m;
                v = ((const float4*)(A + (size_t)ar * K + kt))[c4];
            }
            At[f][c4 * 4 + 0] = v.x; At[f][c4 * 4 + 1] = v.y;
            At[f][c4 * 4 + 2] = v.z; At[f][c4 * 4 + 3] = v.w;
        }
        for (int i = tid; i < 2048; i += 256) {
            int lr = i >> 4, c4 = i & 15;
            float4 v = ((const float4*)(Wv + (size_t)(nt * 128 + lr) * K + kt))[c4];
            Wt[lr][c4 * 4 + 0] = v.x; Wt[lr][c4 * 4 + 1] = v.y;
            Wt[lr][c4 * 4 + 2] = v.z; Wt[lr][c4 * 4 + 3] = v.w;
        }
        __syncthreads();
        const float2* w0p = (const float2*)(&Wt[lr0][0]);
        const float2* w1p = (const float2*)(&Wt[lr1][0]);
#pragma unroll 8
        for (int kh = 0; kh < 32; ++kh) {
            float2 w0 = w0p[kh], w1 = w1p[kh];
#pragma unroll
            for (int j = 0; j < 4; ++j) {
                float2 av = ((const float2*)(&At[4 * fq + j][0]))[kh];
                acc0[j] += w0.x * av.x + w0.y * av.y;
                acc1[j] += w1.x * av.x + w1.y * av.y;
            }
        }
        __syncthreads();
    }
#pragma unroll
    for (int j = 0; j < 4; ++j) {
        int m = mt * 16 + 4 * fq + j;
        if (m < M) {
            C[(size_t)m * 2048 + n0] = acc0[j];
            C[(size_t)m * 2048 + n1] = acc1[j];
        }
    }
}

// ---------------------------------------------------------------------------
// Pyramidal bi-LSTM recurrence. grid 128 = dir(2) x blk(64); 8 dims/block.
// ---------------------------------------------------------------------------
__global__ void __launch_bounds__(256) pyr_rec(
    const float* __restrict__ xpF, const float* __restrict__ xpB,
    const float* __restrict__ WhhF, const float* __restrict__ WhhB,
    float* __restrict__ hbuf,  // [buf2][dir2][512]
    float* __restrict__ outF, float* __restrict__ outB,
    int steps, int* __restrict__ flagF, int* __restrict__ flagB)
{
    const int tid = threadIdx.x;
    const int dir = blockIdx.x >> 6, blk = blockIdx.x & 63;
    const float* xp  = dir ? xpB : xpF;
    const float* Whh = dir ? WhhB : WhhF;
    float* outp = dir ? outB : outF;
    int* flag = dir ? flagB : flagF;

    __shared__ float Wl[32][516];
    __shared__ float hcur[512];
    __shared__ float red[32][9];
    __shared__ float gv[32];

    for (int i = tid; i < 4096; i += 256) {
        int lr = i >> 7, c4 = i & 127;
        int grow = (lr >> 3) * 512 + blk * 8 + (lr & 7);
        float4 v = ((const float4*)(Whh + (size_t)grow * 512))[c4];
        *(float4*)&Wl[lr][c4 * 4] = v;
    }
    float creg = 0.f;
    const int lr = tid & 31, seg = tid >> 5;
    __syncthreads();

    for (int t = 0; t < steps; ++t) {
        if (t > 0) {
            if (tid < 64) wait_flag_ge(&flag[tid * 32], t);
        }
        __syncthreads();
        int hb = t & 1;
        for (int i = tid; i < 512; i += 256)
            hcur[i] = gld(&hbuf[(hb * 2 + dir) * 512 + i]);
        __syncthreads();

        const float* wr = &Wl[lr][seg * 64];
        const float* hr = &hcur[seg * 64];
        float a = 0.f;
#pragma unroll
        for (int k4 = 0; k4 < 16; ++k4) {
            float4 w = *(const float4*)(wr + 4 * k4);
            float4 h4 = *(const float4*)(hr + 4 * k4);
            a += w.x*h4.x + w.y*h4.y + w.z*h4.z + w.w*h4.w;
        }
        red[lr][seg] = a;
        __syncthreads();

        if (tid < 32) {
            int grow = (tid >> 3) * 512 + blk * 8 + (tid & 7);
            float g = xp[(size_t)t * 2048 + grow];
#pragma unroll
            for (int s2 = 0; s2 < 8; ++s2) g += red[tid][s2];
            gv[tid] = g;
        }
        __syncthreads();
        if (tid < 8) {
            float i_ = sigf(gv[tid]), f_ = sigf(gv[8 + tid]);
            float g_ = tanh_f(gv[16 + tid]), o_ = sigf(gv[24 + tid]);
            creg = f_ * creg + i_ * g_;
            float hn = o_ * tanh_f(creg);
            int d = blk * 8 + tid;
            gst(&hbuf[((1 - hb) * 2 + dir) * 512 + d], hn);
            int row = dir ? (steps - 1 - t) : t;
            outp[(size_t)row * 512 + d] = hn;
        }
        __syncthreads();   // drains vmcnt before flag set
        if (tid == 0) set_flag(&flag[blk * 32], t + 1);
    }
}

__global__ void x2_assemble(const float* __restrict__ f1, const float* __restrict__ b1o,
                            float* __restrict__ x2)
{
    int j = blockIdx.x;
    for (int k = threadIdx.x; k < 2048; k += 256) {
        int q = k >> 9, r = k & 511;
        const float* src = (q & 1) ? b1o : f1;
        int row = 2 * j + (q >> 1);
        x2[(size_t)j * 2048 + k] = src[(size_t)row * 512 + r];
    }
}

__global__ void ctx_k(const float* __restrict__ f2, const float* __restrict__ b2o,
                      float* __restrict__ ctx, float* __restrict__ hdec, float* __restrict__ inp)
{
    int j = blockIdx.x;
    for (int k = threadIdx.x; k < 1024; k += 256)
        ctx[(size_t)j * 1024 + k] = (k < 512) ? f2[(size_t)j * 512 + k]
                                              : b2o[(size_t)j * 512 + k - 512];
    if (j == 0) {
        for (int i = threadIdx.x; i < 512; i += 256) hdec[i] = f2[59 * 512 + i];
        if (threadIdx.x < 8) inp[threadIdx.x] = (threadIdx.x == 7) ? 1.f : 0.f;
    }
}

// ---------------------------------------------------------------------------
// Decoder: 66 blocks, dependency-shaped epoch flags.
// ---------------------------------------------------------------------------
__global__ void __launch_bounds__(256) dec_k(
    const float* __restrict__ attn_W, const float* __restrict__ attn_b,
    const float* __restrict__ comb_W, const float* __restrict__ comb_b,
    const float* __restrict__ gWih, const float* __restrict__ gWhh,
    const float* __restrict__ gbih, const float* __restrict__ gbhh,
    const float* __restrict__ outW, const float* __restrict__ outb,
    const float* __restrict__ ctx,
    float* __restrict__ hdec, float* __restrict__ inp,
    float* __restrict__ applied, float* __restrict__ obuf,
    float* __restrict__ dout,
    int* __restrict__ flagA, int* __restrict__ flagB, int* __restrict__ flagC)
{
    const int tid = threadIdx.x, bid = blockIdx.x;
    __shared__ float pool[33056];
    __shared__ float hl[512];
    __shared__ float xl[1036];
    __shared__ float inpl[8];
    __shared__ float red4[60][5];
    __shared__ float red8[24][9];
    __shared__ float red32[8][33];
    __shared__ float ghl[24], gil[24];
    __shared__ float zz[60], aw[60], zd[8];
    __shared__ float ms[1];

    const bool attn_role = (bid < 2);
    float* ctxL = pool;                       // [60][516]
    float* Wg = pool;                         // [24][516]
    float* Wi = pool + 24 * 516;              // [24][516]
    float* Wc = pool + 48 * 516;              // [8][1036]
    const int gbid = bid - 2;
    const int dbase = gbid * 8;

    if (attn_role) {
        for (int i = tid; i < 7680; i += 256) {
            int j = i >> 7, c4 = i & 127;
            float4 v = ((const float4*)(ctx + (size_t)j * 1024 + bid * 512))[c4];
            *(float4*)&ctxL[j * 516 + c4 * 4] = v;
        }
    } else {
        for (int i = tid; i < 3072; i += 256) {
            int r = i >> 7, c4 = i & 127;
            int grow = (r >> 3) * 512 + dbase + (r & 7);
            *(float4*)&Wg[r * 516 + c4 * 4] = ((const float4*)(gWhh + (size_t)grow * 512))[c4];
            *(float4*)&Wi[r * 516 + c4 * 4] = ((const float4*)(gWih + (size_t)grow * 512))[c4];
        }
        for (int i = tid; i < 2064; i += 256) {
            int r = i / 258, c4 = i % 258;
            *(float4*)&Wc[r * 1036 + c4 * 4] =
                ((const float4*)(comb_W + (size_t)(dbase + r) * 1032))[c4];
        }
    }
    __syncthreads();

    for (int s = 0; s < 30; ++s) {
        if (s > 0) {
            if (tid < 64) wait_flag_ge(&flagC[tid * 32], s);
        }
        __syncthreads();
        for (int i = tid; i < 512; i += 256) hl[i] = gld(&hdec[i]);
        __syncthreads();

        if (attn_role) {
            if (s > 0) {
                {
                    int row = tid >> 5, sg = tid & 31;
                    const float* wr = outW + (size_t)row * 512 + sg * 16;
                    const float* hp = hl + sg * 16;
                    float a = 0.f;
#pragma unroll
                    for (int k = 0; k < 16; ++k) a += wr[k] * hp[k];
                    red32[row][sg] = a;
                }
                __syncthreads();
                if (tid < 8) {
                    float a = outb[tid];
#pragma unroll
                    for (int g2 = 0; g2 < 32; ++g2) a += red32[tid][g2];
                    zd[tid] = a;
                }
                __syncthreads();
                if (tid == 0) {
                    float m = zd[0];
                    for (int l = 1; l < 8; ++l) m = fmaxf(m, zd[l]);
                    float ss = 0.f;
                    for (int l = 0; l < 8; ++l) ss += __expf(zd[l] - m);
                    ms[0] = m + __logf(ss);
                }
                __syncthreads();
                if (tid < 8) {
                    float lp = zd[tid] - ms[0];
                    inpl[tid] = lp;
                    if (bid == 0) { dout[(s - 1) * 8 + tid] = lp; gst(&inp[tid], lp); }
                }
            } else {
                if (tid < 8) inpl[tid] = gld(&inp[tid]);
            }
            __syncthreads();
            {
                int r = tid >> 2, sg = tid & 3;
                if (r < 60) {
                    int k0 = sg * 130;
                    const float* wr = attn_W + (size_t)r * 520 + k0;
                    float a = 0.f;
                    for (int k = 0; k < 130; ++k) {
                        int kk = k0 + k;
                        float x = (kk < 8) ? inpl[kk] : hl[kk - 8];
                        a += wr[k] * x;
                    }
                    red4[r][sg] = a;
                }
            }
            __syncthreads();
            if (tid < 60)
                zz[tid] = attn_b[tid] + red4[tid][0] + red4[tid][1] + red4[tid][2] + red4[tid][3];
            __syncthreads();
            if (tid == 0) {
                float m = zz[0];
                for (int j = 1; j < 60; ++j) m = fmaxf(m, zz[j]);
                float ss = 0.f;
                for (int j = 0; j < 60; ++j) { float e = __expf(zz[j] - m); aw[j] = e; ss += e; }
                float inv = 1.f / ss;
                for (int j = 0; j < 60; ++j) aw[j] *= inv;
            }
            __syncthreads();
            for (int cc = tid; cc < 512; cc += 256) {
                float a = 0.f;
                for (int j = 0; j < 60; ++j) a += aw[j] * ctxL[j * 516 + cc];
                gst(&applied[bid * 512 + cc], a);
            }
            __syncthreads();   // drains vmcnt before flag set
            if (tid == 0) set_flag(&flagA[bid * 32], s + 1);
        } else {
            {
                if (tid < 192) {
                    int r = tid >> 3, sg = tid & 7;
                    const float* wr = Wg + r * 516 + sg * 64;
                    const float* hp = hl + sg * 64;
                    float a = 0.f;
#pragma unroll
                    for (int k4 = 0; k4 < 16; ++k4) {
                        float4 w = *(const float4*)(wr + 4 * k4);
                        float4 h4 = *(const float4*)(hp + 4 * k4);
                        a += w.x*h4.x + w.y*h4.y + w.z*h4.z + w.w*h4.w;
                    }
                    red8[r][sg] = a;
                }
            }
            __syncthreads();
            if (tid < 24) {
                int grow = (tid >> 3) * 512 + dbase + (tid & 7);
                float a = gbhh[grow];
#pragma unroll
                for (int g2 = 0; g2 < 8; ++g2) a += red8[tid][g2];
                ghl[tid] = a;
            }
            if (tid < 2) wait_flag_ge(&flagA[tid * 32], s + 1);
            __syncthreads();
            if (tid < 8) xl[tid] = gld(&inp[tid]);
            for (int i = tid; i < 1024; i += 256) xl[8 + i] = gld(&applied[i]);
            __syncthreads();
            {
                int row = tid >> 5, sg = tid & 31;
                const float* wr = Wc + row * 1036;
                float a = 0.f;
                for (int k = sg; k < 1032; k += 32) a += wr[k] * xl[k];
                red32[row][sg] = a;
            }
            __syncthreads();
            if (tid < 8) {
                float a = comb_b[dbase + tid];
#pragma unroll
                for (int g2 = 0; g2 < 32; ++g2) a += red32[tid][g2];
                gst(&obuf[dbase + tid], fmaxf(a, 0.f));
            }
            __syncthreads();   // drains vmcnt before flag set
            if (tid == 0) set_flag(&flagB[gbid * 32], s + 1);
            if (tid < 64) wait_flag_ge(&flagB[tid * 32], s + 1);
            __syncthreads();
            for (int i = tid; i < 512; i += 256) xl[i] = gld(&obuf[i]);
            __syncthreads();
            {
                if (tid < 192) {
                    int r = tid >> 3, sg = tid & 7;
                    const float* wr = Wi + r * 516 + sg * 64;
                    const float* op = xl + sg * 64;
                    float a = 0.f;
#pragma unroll
                    for (int k4 = 0; k4 < 16; ++k4) {
                        float4 w = *(const float4*)(wr + 4 * k4);
                        float4 o4 = *(const float4*)(op + 4 * k4);
                        a += w.x*o4.x + w.y*o4.y + w.z*o4.z + w.w*o4.w;
                    }
                    red8[r][sg] = a;
                }
            }
            __syncthreads();
            if (tid < 24) {
                int grow = (tid >> 3) * 512 + dbase + (tid & 7);
                float a = gbih[grow];
#pragma unroll
                for (int g2 = 0; g2 < 8; ++g2) a += red8[tid][g2];
                gil[tid] = a;
            }
            __syncthreads();
            if (tid < 8) {
                float r_ = sigf(gil[tid] + ghl[tid]);
                float z_ = sigf(gil[8 + tid] + ghl[8 + tid]);
                float n_ = tanh_f(gil[16 + tid] + r_ * ghl[16 + tid]);
                float hnew = (1.f - z_) * n_ + z_ * hl[dbase + tid];
                gst(&hdec[dbase + tid], hnew);
            }
            __syncthreads();   // drains vmcnt before flag set
            if (tid == 0) set_flag(&flagC[gbid * 32], s + 1);
        }
    }

    if (bid == 0) {
        if (tid < 64) wait_flag_ge(&flagC[tid * 32], 30);
        __syncthreads();
        for (int i = tid; i < 512; i += 256) hl[i] = gld(&hdec[i]);
        __syncthreads();
        {
            int row = tid >> 5, sg = tid & 31;
            const float* wr = outW + (size_t)row * 512 + sg * 16;
            const float* hp = hl + sg * 16;
            float a = 0.f;
#pragma unroll
            for (int k = 0; k < 16; ++k) a += wr[k] * hp[k];
            red32[row][sg] = a;
        }
        __syncthreads();
        if (tid < 8) {
            float a = outb[tid];
#pragma unroll
            for (int g2 = 0; g2 < 32; ++g2) a += red32[tid][g2];
            zd[tid] = a;
        }
        __syncthreads();
        if (tid == 0) {
            float m = zd[0];
            for (int l = 1; l < 8; ++l) m = fmaxf(m, zd[l]);
            float ss = 0.f;
            for (int l = 0; l < 8; ++l) ss += __expf(zd[l] - m);
            ms[0] = m + __logf(ss);
        }
        __syncthreads();
        if (tid < 8) dout[29 * 8 + tid] = zd[tid] - ms[0];
    }
}

// ---------------------------------------------------------------------------
extern "C" void kernel_launch(void* const* d_in, const int* in_sizes, int n_in,
                              void* d_out, int out_size, void* d_ws, size_t ws_size,
                              hipStream_t stream) {
    (void)in_sizes; (void)n_in; (void)out_size; (void)ws_size;
    const float* data    = (const float*)d_in[0];
    const float* enc_Wih = (const float*)d_in[1];
    const float* enc_Whh = (const float*)d_in[2];
    const float* enc_bih = (const float*)d_in[3];
    const float* enc_bhh = (const float*)d_in[4];
    const float* p1f_Wih = (const float*)d_in[5];
    const float* p1f_Whh = (const float*)d_in[6];
    const float* p1f_bih = (const float*)d_in[7];
    const float* p1f_bhh = (const float*)d_in[8];
    const float* p1b_Wih = (const float*)d_in[9];
    const float* p1b_Whh = (const float*)d_in[10];
    const float* p1b_bih = (const float*)d_in[11];
    const float* p1b_bhh = (const float*)d_in[12];
    const float* p2f_Wih = (const float*)d_in[13];
    const float* p2f_Whh = (const float*)d_in[14];
    const float* p2f_bih = (const float*)d_in[15];
    const float* p2f_bhh = (const float*)d_in[16];
    const float* p2b_Wih = (const float*)d_in[17];
    const float* p2b_Whh = (const float*)d_in[18];
    const float* p2b_bih = (const float*)d_in[19];
    const float* p2b_bhh = (const float*)d_in[20];
    const float* attn_W  = (const float*)d_in[21];
    const float* attn_b  = (const float*)d_in[22];
    const float* comb_W  = (const float*)d_in[23];
    const float* comb_b  = (const float*)d_in[24];
    const float* gru_Wih = (const float*)d_in[25];
    const float* gru_Whh = (const float*)d_in[26];
    const float* gru_bih = (const float*)d_in[27];
    const float* gru_bhh = (const float*)d_in[28];
    const float* out_W   = (const float*)d_in[29];
    const float* out_b   = (const float*)d_in[30];

    float* ws = (float*)d_ws;
    // zeroed region [0 .. 147008)
    unsigned long long* hbufF = (unsigned long long*)ws;  // 122880 words (61440 ull)
    float* ph1      = ws + 122880;           // 2048
    float* ph2      = ws + 124928;           // 2048
    int* flagsE     = (int*)(ws + 126976);   // 7680
    int* flagsP1F   = (int*)(ws + 134656);   // 2048
    int* flagsP1B   = (int*)(ws + 136704);   // 2048
    int* flagsP2F   = (int*)(ws + 138752);   // 2048
    int* flagsP2B   = (int*)(ws + 140800);   // 2048
    int* flagsDA    = (int*)(ws + 142848);   // 64
    int* flagsDB    = (int*)(ws + 142912);   // 2048
    int* flagsDC    = (int*)(ws + 144960);   // 2048  -> zero end = 147008
    // non-zeroed scratch
    float* henc  = ws + 147008;              // 122880
    float* xp1f  = ws + 269888;              // 245760
    float* xp1b  = ws + 515648;              // 245760
    float* f1    = ws + 761408;              // 61440
    float* b1o   = ws + 822848;              // 61440
    float* x2    = ws + 884288;              // 122880
    float* xp2f  = ws + 1007168;             // 122880
    float* xp2b  = ws + 1130048;             // 122880
    float* f2    = ws + 1252928;             // 30720
    float* b2o   = ws + 1283648;             // 30720
    float* ctxb  = ws + 1314368;             // 61440
    float* hdec  = ws + 1375808;             // 512
    float* inp   = ws + 1376320;             // 16
    float* appl  = ws + 1376336;             // 1024
    float* obuf  = ws + 1377360;             // 512

    init_k<<<256, 256, 0, stream>>>(ws);

    enc_all<<<240, 256, 0, stream>>>(data, enc_Wih, enc_Whh, enc_bih, enc_bhh,
                                     hbufF, henc, flagsE);
    // henc = final h (240x512) fp32; x1 = henc.reshape(120,1024)
    gemm_xp<<<128, 256, 0, stream>>>(henc, 120, 1024, 0, p1f_Wih, p1f_bih, p1f_bhh, xp1f);
    gemm_xp<<<128, 256, 0, stream>>>(henc, 120, 1024, 1, p1b_Wih, p1b_bih, p1b_bhh, xp1b);
    pyr_rec<<<128, 256, 0, stream>>>(xp1f, xp1b, p1f_Whh, p1b_Whh, ph1, f1, b1o, 120,
                                     flagsP1F, flagsP1B);
    x2_assemble<<<60, 256, 0, stream>>>(f1, b1o, x2);
    gemm_xp<<<64, 256, 0, stream>>>(x2, 60, 2048, 0, p2f_Wih, p2f_bih, p2f_bhh, xp2f);
    gemm_xp<<<64, 256, 0, stream>>>(x2, 60, 2048, 1, p2b_Wih, p2b_bih, p2b_bhh, xp2b);
    pyr_rec<<<128, 256, 0, stream>>>(xp2f, xp2b, p2f_Whh, p2b_Whh, ph2, f2, b2o, 60,
                                     flagsP2F, flagsP2B);
    ctx_k<<<60, 256, 0, stream>>>(f2, b2o, ctxb, hdec, inp);
    dec_k<<<66, 256, 0, stream>>>(attn_W, attn_b, comb_W, comb_b,
                                  gru_Wih, gru_Whh, gru_bih, gru_bhh,
                                  out_W, out_b, ctxb, hdec, inp, appl, obuf,
                                  (float*)d_out, flagsDA, flagsDB, flagsDC);
}